// Round 13
// baseline (63.120 us; speedup 1.0000x reference)
//
#include <hip/hip_runtime.h>
#include <cmath>

#define DEV static __device__ __forceinline__

namespace {

constexpr int B = 2, S = 512, D = 512, H = 8;  // dh = 64
constexpr int BS = B * S;                      // 1024 token rows
constexpr float EPSF = 1e-5f;
constexpr float MAXN = 1.0f - 1e-3f;           // MAX_NORM / sqrt(c)
constexpr int NSPLIT = 4;                      // K-splits in attention

typedef unsigned short u16;
typedef unsigned int u32;
typedef __attribute__((ext_vector_type(8))) short bf8_t;    // bf16x8 (16B)
typedef __attribute__((ext_vector_type(8))) _Float16 h8_t;  // f16x8
typedef __attribute__((ext_vector_type(4))) float f4_t;

DEV u16 f2bf(float f) {  // RNE bf16
  u32 x = __float_as_uint(f);
  u32 r = x + 0x7fffu + ((x >> 16) & 1u);
  return (u16)(r >> 16);
}
DEV float bf2f(u16 u) { return __uint_as_float(((u32)u) << 16); }
DEV u16 f2h(float f) {
  _Float16 h = (_Float16)f;
  u16 u;
  __builtin_memcpy(&u, &h, 2);
  return u;
}
DEV float tanh_pos(float n) {  // tanh for n >= 0
  float e = __builtin_amdgcn_exp2f(2.8853900817779268f * n);  // e^(2n)
  return (e - 1.f) / (e + 1.f);
}
DEV bf8_t conv8(float4 a, float4 b) {
  bf8_t o;
  o[0] = (short)f2bf(a.x); o[1] = (short)f2bf(a.y);
  o[2] = (short)f2bf(a.z); o[3] = (short)f2bf(a.w);
  o[4] = (short)f2bf(b.x); o[5] = (short)f2bf(b.y);
  o[6] = (short)f2bf(b.z); o[7] = (short)f2bf(b.w);
  return o;
}
DEV bf8_t conv8v(f4_t a, f4_t b, float f) {
  bf8_t o;
  o[0] = (short)f2bf(a[0] * f); o[1] = (short)f2bf(a[1] * f);
  o[2] = (short)f2bf(a[2] * f); o[3] = (short)f2bf(a[3] * f);
  o[4] = (short)f2bf(b[0] * f); o[5] = (short)f2bf(b[1] * f);
  o[6] = (short)f2bf(b[2] * f); o[7] = (short)f2bf(b[3] * f);
  return o;
}
DEV float dot4(float4 a) { return a.x * a.x + a.y * a.y + a.z * a.z + a.w * a.w; }

// ---------------- QKV GEMM, logmap post-GEMM + accumulator zeroing ---------
// Stages raw fp32 A -> bf16 while accumulating per-row fp32 norm^2; epilogue
// applies fac(row) via linearity, then expmap (z<2) or vT f16 (z=2).
// Each block also zeroes its slice of the Osum|rsum|rnorm|scnt region.
__global__ __launch_bounds__(256) void gemm_qkv_f2z(
    const float* __restrict__ q, const float* __restrict__ k,
    const float* __restrict__ v, const float* __restrict__ Wq,
    const float* __restrict__ Wk, const float* __restrict__ Wv,
    const float* __restrict__ bq, const float* __restrict__ bk,
    const float* __restrict__ bv, u16* __restrict__ hq, u16* __restrict__ hk,
    u16* __restrict__ vT, float* __restrict__ qn2, float* __restrict__ kn2,
    f4_t* __restrict__ zero4, int nzero4) {
  const int z = blockIdx.z;
  const float* A = z == 0 ? q : (z == 1 ? k : v);
  const float* W = z == 0 ? Wq : (z == 1 ? Wk : Wv);
  const float* bias = z == 0 ? bq : (z == 1 ? bk : bv);
  const int i0 = blockIdx.y * 64, j0 = blockIdx.x * 64, h = blockIdx.x;
  __shared__ __align__(16) u16 As[4096], Bs[4096];
  __shared__ float facs[64];
  const int tid = threadIdx.x;
  const int w = tid >> 6, l = tid & 63, lg = l >> 4, lr = l & 15;
  const int srow = tid >> 3, scb = tid & 7;
  // zero the attention accumulator region (ordered by kernel boundary)
  {
    const int bid = blockIdx.z * 128 + blockIdx.y * 8 + blockIdx.x;
    const f4_t zv = {0, 0, 0, 0};
    for (int i = bid * 256 + tid; i < nzero4; i += 384 * 256) zero4[i] = zv;
  }
  f4_t acc[4] = {{0, 0, 0, 0}, {0, 0, 0, 0}, {0, 0, 0, 0}, {0, 0, 0, 0}};
  float n2a = 0.f, n2b = 0.f;  // row-norm^2 partials (this thread's 8 cols)
  for (int kt = 0; kt < D; kt += 64) {
    const float* ap0 = A + (size_t)(i0 + srow) * D + kt + scb * 8;
    const float* ap1 = ap0 + (size_t)32 * D;
    const float* wp0 = W + (size_t)(j0 + srow) * D + kt + scb * 8;
    const float* wp1 = wp0 + (size_t)32 * D;
    float4 a00 = *(const float4*)ap0, a01 = *(const float4*)(ap0 + 4);
    float4 a10 = *(const float4*)ap1, a11 = *(const float4*)(ap1 + 4);
    float4 w00 = *(const float4*)wp0, w01 = *(const float4*)(wp0 + 4);
    float4 w10 = *(const float4*)wp1, w11 = *(const float4*)(wp1 + 4);
    n2a += dot4(a00) + dot4(a01);
    n2b += dot4(a10) + dot4(a11);
    __syncthreads();  // previous iteration's LDS frag reads done
    const int sw = 8 * (scb ^ (srow & 7));
    *(bf8_t*)&As[srow * 64 + sw] = conv8(a00, a01);
    *(bf8_t*)&As[(srow + 32) * 64 + sw] = conv8(a10, a11);
    *(bf8_t*)&Bs[srow * 64 + sw] = conv8(w00, w01);
    *(bf8_t*)&Bs[(srow + 32) * 64 + sw] = conv8(w10, w11);
    __syncthreads();
#pragma unroll
    for (int ks = 0; ks < 2; ++ks) {
      const int arow = w * 16 + lr;
      bf8_t af = *(const bf8_t*)&As[arow * 64 + 8 * ((ks * 4 + lg) ^ (arow & 7))];
#pragma unroll
      for (int nf = 0; nf < 4; ++nf) {
        const int brow = nf * 16 + lr;
        bf8_t bfr = *(const bf8_t*)&Bs[brow * 64 + 8 * ((ks * 4 + lg) ^ (brow & 7))];
        acc[nf] = __builtin_amdgcn_mfma_f32_16x16x32_bf16(af, bfr, acc[nf], 0, 0, 0);
      }
    }
  }
  // row logmap factors: reduce norm^2 over the 8 scb lanes (consecutive)
  n2a += __shfl_xor(n2a, 1, 64); n2a += __shfl_xor(n2a, 2, 64);
  n2a += __shfl_xor(n2a, 4, 64);
  n2b += __shfl_xor(n2b, 1, 64); n2b += __shfl_xor(n2b, 2, 64);
  n2b += __shfl_xor(n2b, 4, 64);
  if (scb == 0) {
    float na = fmaxf(sqrtf(n2a), EPSF), za = fminf(na, 1.0f - EPSF);
    facs[srow] = 0.34657359027997264f *
                 __builtin_amdgcn_logf((1.0f + za) / (1.0f - za)) / na;
    float nb = fmaxf(sqrtf(n2b), EPSF), zb = fminf(nb, 1.0f - EPSF);
    facs[srow + 32] = 0.34657359027997264f *
                      __builtin_amdgcn_logf((1.0f + zb) / (1.0f - zb)) / nb;
  }
  __syncthreads();
  float c[4][4];
#pragma unroll
  for (int nf = 0; nf < 4; ++nf) {
    const float bb = bias[j0 + nf * 16 + lr];
#pragma unroll
    for (int r = 0; r < 4; ++r)
      c[nf][r] = acc[nf][r] * facs[w * 16 + lg * 4 + r] + bb;
  }
  if (z < 2) {
    float part[4] = {0, 0, 0, 0};
#pragma unroll
    for (int nf = 0; nf < 4; ++nf)
#pragma unroll
      for (int r = 0; r < 4; ++r) part[r] += c[nf][r] * c[nf][r];
#pragma unroll
    for (int off = 1; off < 16; off <<= 1)
#pragma unroll
      for (int r = 0; r < 4; ++r) part[r] += __shfl_xor(part[r], off, 64);
    float fac[4];
#pragma unroll
    for (int r = 0; r < 4; ++r) {
      float n = fmaxf(sqrtf(part[r]), EPSF);
      fac[r] = fminf(tanh_pos(n), MAXN) / n;
    }
    u16 yb[4][4];
    float p2[4] = {0, 0, 0, 0};
#pragma unroll
    for (int nf = 0; nf < 4; ++nf)
#pragma unroll
      for (int r = 0; r < 4; ++r) {
        u16 t = f2bf(c[nf][r] * fac[r]);
        yb[nf][r] = t;
        float yf = bf2f(t);
        p2[r] += yf * yf;  // norm^2 of the rounded point
      }
#pragma unroll
    for (int off = 1; off < 16; off <<= 1)
#pragma unroll
      for (int r = 0; r < 4; ++r) p2[r] += __shfl_xor(p2[r], off, 64);
    u16* dst = z == 0 ? hq : hk;
    float* n2o = z == 0 ? qn2 : kn2;
#pragma unroll
    for (int nf = 0; nf < 4; ++nf)
#pragma unroll
      for (int r = 0; r < 4; ++r)
        dst[(size_t)(i0 + w * 16 + lg * 4 + r) * D + j0 + nf * 16 + lr] = yb[nf][r];
    if (lr == 0)
#pragma unroll
      for (int r = 0; r < 4; ++r)
        n2o[h * BS + i0 + w * 16 + lg * 4 + r] = p2[r];
  } else {
    // V: f16, transpose via LDS -> vT[(b*8+h)*64 + d][s]
    __syncthreads();
#pragma unroll
    for (int nf = 0; nf < 4; ++nf)
#pragma unroll
      for (int r = 0; r < 4; ++r) {
        const int prow = w * 16 + lg * 4 + r;  // local token s
        const int pcol = nf * 16 + lr;         // local d
        As[prow * 64 + 8 * ((pcol >> 3) ^ (prow & 7)) + (pcol & 7)] = f2h(c[nf][r]);
      }
    __syncthreads();
    const int d = tid >> 2, s0 = (tid & 3) * 16;
    const int b = i0 >> 9, sb = (i0 & 511) + s0;
    bf8_t o0, o1;
#pragma unroll
    for (int j = 0; j < 8; ++j) {
      const int s = s0 + j;
      o0[j] = (short)As[s * 64 + 8 * ((d >> 3) ^ (s & 7)) + (d & 7)];
    }
#pragma unroll
    for (int j = 0; j < 8; ++j) {
      const int s = s0 + 8 + j;
      o1[j] = (short)As[s * 64 + 8 * ((d >> 3) ^ (s & 7)) + (d & 7)];
    }
    u16* dst = vT + ((size_t)((b * 8 + h) * 64 + d)) * S + sb;
    *(bf8_t*)dst = o0;
    *(bf8_t*)(dst + 8) = o1;
  }
}

// ---------------- fused attention, split-K x4, producer-side atomic combine
// Unnormalized PV partials accumulate via device-scope atomicAdd into
// Osum[bh][q][64]; exp-sums into rsum[bh*S+q]. (Zeroed by gemm_qkv_f2z.)
__global__ __launch_bounds__(64) void fused_attn_at(
    const u16* __restrict__ hq, const u16* __restrict__ hk,
    const u16* __restrict__ vT, const float* __restrict__ qn2,
    const float* __restrict__ kn2, float* __restrict__ Osum,
    float* __restrict__ rsum) {
  const int bh = blockIdx.z, b = bh >> 3, h = bh & 7;
  const int i0 = blockIdx.x * 16;
  const int sp = blockIdx.y;
  __shared__ __align__(16) u16 Ps[2][16 * 64];
  const int l = threadIdx.x, lg = l >> 4, lr = l & 15;
  bf8_t qf[2];
#pragma unroll
  for (int ks = 0; ks < 2; ++ks)
    qf[ks] = *(const bf8_t*)(hq + (size_t)(b * S + i0 + lr) * D + h * 64 +
                             ks * 32 + lg * 8);
  float qq[4];
#pragma unroll
  for (int r = 0; r < 4; ++r) qq[r] = qn2[h * BS + b * S + i0 + lg * 4 + r];
  f4_t acc_o[4] = {{0, 0, 0, 0}, {0, 0, 0, 0}, {0, 0, 0, 0}, {0, 0, 0, 0}};
  float rloc[4] = {0, 0, 0, 0};
#pragma unroll
  for (int t = 0; t < 2; ++t) {
    const int kt = sp * 2 + t;
    const int kb = b * S + kt * 64;
    bf8_t kf[2][4], vf[2][4];
#pragma unroll
    for (int ks = 0; ks < 2; ++ks)
#pragma unroll
      for (int nf = 0; nf < 4; ++nf) {
        kf[ks][nf] = *(const bf8_t*)(hk + (size_t)(kb + nf * 16 + lr) * D +
                                     h * 64 + ks * 32 + lg * 8);
        vf[ks][nf] = *(const bf8_t*)(vT + (size_t)(bh * 64 + nf * 16 + lr) * S +
                                     kt * 64 + ks * 32 + lg * 8);
      }
    float kn[4];
#pragma unroll
    for (int nf = 0; nf < 4; ++nf) kn[nf] = kn2[h * BS + kb + nf * 16 + lr];
    f4_t sa[4] = {{0, 0, 0, 0}, {0, 0, 0, 0}, {0, 0, 0, 0}, {0, 0, 0, 0}};
#pragma unroll
    for (int ks = 0; ks < 2; ++ks)
#pragma unroll
      for (int nf = 0; nf < 4; ++nf)
        sa[nf] = __builtin_amdgcn_mfma_f32_16x16x32_bf16(qf[ks], kf[ks][nf],
                                                         sa[nf], 0, 0, 0);
    u16* Pb = Ps[t & 1];
    float ps[4] = {0, 0, 0, 0};
#pragma unroll
    for (int nf = 0; nf < 4; ++nf) {
      const float kk = kn[nf];
#pragma unroll
      for (int r = 0; r < 4; ++r) {
        const float tt = sa[nf][r];
        float num = fmaxf(qq[r] - 2.f * tt + kk, 0.f);
        float den = fmaxf(1.f - 2.f * tt + qq[r] * kk, EPSF);
        float rr = fminf(fmaxf(sqrtf(num / den), EPSF), MAXN);
        // p = ((1-r)/(1+r))^(1/8)
        float p = __builtin_amdgcn_exp2f(
            0.125f * __builtin_amdgcn_logf((1.f - rr) / (1.f + rr)));
        ps[r] += p;
        const int prow = lg * 4 + r, pcol = nf * 16 + lr;
        Pb[prow * 64 + 8 * ((pcol >> 3) ^ (prow & 7)) + (pcol & 7)] = f2h(p);
      }
    }
#pragma unroll
    for (int off = 1; off < 16; off <<= 1)
#pragma unroll
      for (int r = 0; r < 4; ++r) ps[r] += __shfl_xor(ps[r], off, 64);
#pragma unroll
    for (int r = 0; r < 4; ++r) rloc[r] += ps[r];
#pragma unroll
    for (int ks = 0; ks < 2; ++ks) {
      h8_t pa = *(const h8_t*)&Pb[lr * 64 + 8 * ((ks * 4 + lg) ^ (lr & 7))];
#pragma unroll
      for (int nf = 0; nf < 4; ++nf)
        acc_o[nf] = __builtin_amdgcn_mfma_f32_16x16x32_f16(pa, vf[ks][nf],
                                                           acc_o[nf], 0, 0, 0);
    }
  }
  float* Ob = Osum + ((size_t)bh * S + i0) * 64;
#pragma unroll
  for (int nf = 0; nf < 4; ++nf)
#pragma unroll
    for (int r = 0; r < 4; ++r)
      atomicAdd(&Ob[(lg * 4 + r) * 64 + nf * 16 + lr], acc_o[nf][r]);
  if (lr == 0)
#pragma unroll
    for (int r = 0; r < 4; ++r)
      atomicAdd(&rsum[(size_t)bh * S + i0 + lg * 4 + r], rloc[r]);
}

// ---------------- out GEMM: Osum*inv staging + Wo conv + expmap epilogue ---
__global__ __launch_bounds__(256) void gemm_out_fin3(
    const float* __restrict__ Osum, const float* __restrict__ rsum,
    const float* __restrict__ Wo, const float* __restrict__ bo,
    float* __restrict__ olin, float* __restrict__ rnorm,
    u32* __restrict__ scnt, float* __restrict__ out) {
  const int jblk = blockIdx.x, iblk = blockIdx.y;
  const int i0 = iblk * 64, j0 = jblk * 64;
  __shared__ __align__(16) u16 As[4096], Bs[4096];
  __shared__ float invs[512];
  __shared__ float facL[64];
  __shared__ int lastFlag;
  const int tid = threadIdx.x;
  const int w = tid >> 6, l = tid & 63, lg = l >> 4, lr = l & 15;
  const int srow = tid >> 3, scb = tid & 7;
  const int bb = i0 >> 9, sbase = i0 & 511;
  // prologue: per (head, row) inverse softmax sums for this token slab
  for (int e = tid; e < 512; e += 256) {
    const int h = e >> 6, sr = e & 63;
    invs[e] = 1.f / rsum[(size_t)(bb * 8 + h) * S + sbase + sr];
  }
  f4_t acc[4] = {{0, 0, 0, 0}, {0, 0, 0, 0}, {0, 0, 0, 0}, {0, 0, 0, 0}};
  for (int kt = 0; kt < 8; ++kt) {
    const int bh = bb * 8 + kt;  // A-cols kt*64.. are head kt
    const float* p0 = Osum + ((size_t)bh * S + sbase + srow) * 64 + scb * 8;
    f4_t s00 = *(const f4_t*)p0;
    f4_t s01 = *(const f4_t*)(p0 + 4);
    f4_t s10 = *(const f4_t*)(p0 + 32 * 64);
    f4_t s11 = *(const f4_t*)(p0 + 32 * 64 + 4);
    const float* wp0 = Wo + (size_t)(j0 + srow) * D + kt * 64 + scb * 8;
    const float* wp1 = wp0 + (size_t)32 * D;
    float4 w00 = *(const float4*)wp0, w01 = *(const float4*)(wp0 + 4);
    float4 w10 = *(const float4*)wp1, w11 = *(const float4*)(wp1 + 4);
    __syncthreads();  // prev iter LDS reads done; invs visible (iter 0)
    const float inv0 = invs[kt * 64 + srow], inv1 = invs[kt * 64 + srow + 32];
    const int sw = 8 * (scb ^ (srow & 7));
    *(bf8_t*)&As[srow * 64 + sw] = conv8v(s00, s01, inv0);
    *(bf8_t*)&As[(srow + 32) * 64 + sw] = conv8v(s10, s11, inv1);
    *(bf8_t*)&Bs[srow * 64 + sw] = conv8(w00, w01);
    *(bf8_t*)&Bs[(srow + 32) * 64 + sw] = conv8(w10, w11);
    __syncthreads();
#pragma unroll
    for (int ks = 0; ks < 2; ++ks) {
      const int arow = w * 16 + lr;
      bf8_t af = *(const bf8_t*)&As[arow * 64 + 8 * ((ks * 4 + lg) ^ (arow & 7))];
#pragma unroll
      for (int nf = 0; nf < 4; ++nf) {
        const int brow = nf * 16 + lr;
        bf8_t bfr = *(const bf8_t*)&Bs[brow * 64 + 8 * ((ks * 4 + lg) ^ (brow & 7))];
        acc[nf] = __builtin_amdgcn_mfma_f32_16x16x32_bf16(af, bfr, acc[nf], 0, 0, 0);
      }
    }
  }
  float c[4][4];
  float pr[4] = {0, 0, 0, 0};
#pragma unroll
  for (int nf = 0; nf < 4; ++nf) {
    const float bb2 = bo[j0 + nf * 16 + lr];
#pragma unroll
    for (int r = 0; r < 4; ++r) {
      c[nf][r] = acc[nf][r] + bb2;
      pr[r] += c[nf][r] * c[nf][r];
    }
  }
#pragma unroll
  for (int nf = 0; nf < 4; ++nf)
#pragma unroll
    for (int r = 0; r < 4; ++r)
      olin[(size_t)(i0 + w * 16 + lg * 4 + r) * D + j0 + nf * 16 + lr] = c[nf][r];
#pragma unroll
  for (int off = 1; off < 16; off <<= 1)
#pragma unroll
    for (int r = 0; r < 4; ++r) pr[r] += __shfl_xor(pr[r], off, 64);
  if (lr == 0)
#pragma unroll
    for (int r = 0; r < 4; ++r)
      atomicAdd(&rnorm[i0 + w * 16 + lg * 4 + r], pr[r]);
  __syncthreads();
  if (tid == 0) {
    __threadfence();  // release: olin stores + rnorm atomics visible
    u32 old = __hip_atomic_fetch_add(&scnt[iblk], 1u, __ATOMIC_ACQ_REL,
                                     __HIP_MEMORY_SCOPE_AGENT);
    lastFlag = (old == 7);
  }
  __syncthreads();
  if (!lastFlag) return;
  if (tid == 0) __threadfence();  // acquire side
  __syncthreads();
  if (tid < 64) {
    float nn = rnorm[i0 + tid];
    float n = fmaxf(sqrtf(nn), EPSF);
    facL[tid] = fminf(tanh_pos(n), MAXN) / n;
  }
  __syncthreads();
  for (int e = tid; e < 64 * 128; e += 256) {
    const int row = e >> 7, c4 = (e & 127) * 4;
    float4 t = *(const float4*)&olin[(size_t)(i0 + row) * D + c4];
    const float f = facL[row];
    float4 o = make_float4(t.x * f, t.y * f, t.z * f, t.w * f);
    *(float4*)&out[(size_t)(i0 + row) * D + c4] = o;
  }
}

}  // namespace

extern "C" void kernel_launch(void* const* d_in, const int* in_sizes, int n_in,
                              void* d_out, int out_size, void* d_ws,
                              size_t ws_size, hipStream_t stream) {
  const float* q = (const float*)d_in[0];
  const float* k = (const float*)d_in[1];
  const float* v = (const float*)d_in[2];
  const float* Wq = (const float*)d_in[3];
  const float* bq = (const float*)d_in[4];
  const float* Wk = (const float*)d_in[5];
  const float* bk = (const float*)d_in[6];
  const float* Wv = (const float*)d_in[7];
  const float* bv = (const float*)d_in[8];
  const float* Wo = (const float*)d_in[9];
  const float* bo = (const float*)d_in[10];
  float* out = (float*)d_out;

  char* w8 = (char*)d_ws;
  u16* hq = (u16*)(w8 + 0);                 // 1 MB
  u16* hk = (u16*)(w8 + 1048576);           // 1 MB
  u16* vT = (u16*)(w8 + 2097152);           // 1 MB   [bh*64+d][s] f16
  float* qn2 = (float*)(w8 + 3145728);      // 32 KB  [H][BS]
  float* kn2 = (float*)(w8 + 3178496);      // 32 KB  [H][BS]
  float* olin = (float*)(w8 + 3211264);     // 2 MB   fp32
  float* Osum = (float*)(w8 + 5308416);     // 2 MB   [16][512][64]
  float* rsum = (float*)(w8 + 7405568);     // 32 KB  [16][512]
  float* rnorm = (float*)(w8 + 7438336);    // 4 KB   [1024]
  u32* scnt = (u32*)(w8 + 7442432);         // 64 B   [16]
  // zero region: Osum|rsum|rnorm|scnt = 2134080 B = 133380 float4 (exact)
  f4_t* zero4 = (f4_t*)(w8 + 5308416);
  const int nzero4 = 133380;

  gemm_qkv_f2z<<<dim3(8, 16, 3), 256, 0, stream>>>(
      q, k, v, Wq, Wk, Wv, bq, bk, bv, hq, hk, vT, qn2, kn2, zero4, nzero4);
  fused_attn_at<<<dim3(32, NSPLIT, 16), 64, 0, stream>>>(hq, hk, vT, qn2, kn2,
                                                         Osum, rsum);
  gemm_out_fin3<<<dim3(8, 16), 256, 0, stream>>>(Osum, rsum, Wo, bo, olin,
                                                 rnorm, scnt, out);
}

// Round 14
// 41.828 us; speedup vs baseline: 1.5090x; 1.5090x over previous
//
#include <hip/hip_runtime.h>
#include <cmath>

#define DEV static __device__ __forceinline__

namespace {

constexpr int B = 2, S = 512, D = 512, H = 8;  // dh = 64
constexpr int BS = B * S;                      // 1024 token rows
constexpr float EPSF = 1e-5f;
constexpr float MAXN = 1.0f - 1e-3f;           // MAX_NORM / sqrt(c)

typedef unsigned short u16;
typedef unsigned int u32;
typedef __attribute__((ext_vector_type(8))) short bf8_t;    // bf16x8 (16B)
typedef __attribute__((ext_vector_type(8))) _Float16 h8_t;  // f16x8
typedef __attribute__((ext_vector_type(4))) float f4_t;

DEV float waveSum(float v) {
#pragma unroll
  for (int o = 32; o > 0; o >>= 1) v += __shfl_xor(v, o, 64);
  return v;
}
DEV u16 f2bf(float f) {  // RNE bf16
  u32 x = __float_as_uint(f);
  u32 r = x + 0x7fffu + ((x >> 16) & 1u);
  return (u16)(r >> 16);
}
DEV float bf2f(u16 u) { return __uint_as_float(((u32)u) << 16); }
DEV u16 f2h(float f) {
  _Float16 h = (_Float16)f;
  u16 u;
  __builtin_memcpy(&u, &h, 2);
  return u;
}
DEV float tanh_pos(float n) {  // tanh for n >= 0
  float e = __builtin_amdgcn_exp2f(2.8853900817779268f * n);  // e^(2n)
  return (e - 1.f) / (e + 1.f);
}
DEV bf8_t conv8(float4 a, float4 b) {
  bf8_t o;
  o[0] = (short)f2bf(a.x); o[1] = (short)f2bf(a.y);
  o[2] = (short)f2bf(a.z); o[3] = (short)f2bf(a.w);
  o[4] = (short)f2bf(b.x); o[5] = (short)f2bf(b.y);
  o[6] = (short)f2bf(b.z); o[7] = (short)f2bf(b.w);
  return o;
}
DEV float dot4(float4 a) { return a.x * a.x + a.y * a.y + a.z * a.z + a.w * a.w; }

// ---------------- QKV GEMM, logmap applied post-GEMM (linearity) -----------
// (R12's proven kernel, unchanged.)
__global__ __launch_bounds__(256) void gemm_qkv_f2(
    const float* __restrict__ q, const float* __restrict__ k,
    const float* __restrict__ v, const float* __restrict__ Wq,
    const float* __restrict__ Wk, const float* __restrict__ Wv,
    const float* __restrict__ bq, const float* __restrict__ bk,
    const float* __restrict__ bv, u16* __restrict__ hq, u16* __restrict__ hk,
    u16* __restrict__ vT, float* __restrict__ qn2, float* __restrict__ kn2) {
  const int z = blockIdx.z;
  const float* A = z == 0 ? q : (z == 1 ? k : v);
  const float* W = z == 0 ? Wq : (z == 1 ? Wk : Wv);
  const float* bias = z == 0 ? bq : (z == 1 ? bk : bv);
  const int i0 = blockIdx.y * 64, j0 = blockIdx.x * 64, h = blockIdx.x;
  __shared__ __align__(16) u16 As[4096], Bs[4096];
  __shared__ float facs[64];
  const int tid = threadIdx.x;
  const int w = tid >> 6, l = tid & 63, lg = l >> 4, lr = l & 15;
  const int srow = tid >> 3, scb = tid & 7;
  f4_t acc[4] = {{0, 0, 0, 0}, {0, 0, 0, 0}, {0, 0, 0, 0}, {0, 0, 0, 0}};
  float n2a = 0.f, n2b = 0.f;  // row-norm^2 partials (this thread's 8 cols)
  for (int kt = 0; kt < D; kt += 64) {
    const float* ap0 = A + (size_t)(i0 + srow) * D + kt + scb * 8;
    const float* ap1 = ap0 + (size_t)32 * D;
    const float* wp0 = W + (size_t)(j0 + srow) * D + kt + scb * 8;
    const float* wp1 = wp0 + (size_t)32 * D;
    float4 a00 = *(const float4*)ap0, a01 = *(const float4*)(ap0 + 4);
    float4 a10 = *(const float4*)ap1, a11 = *(const float4*)(ap1 + 4);
    float4 w00 = *(const float4*)wp0, w01 = *(const float4*)(wp0 + 4);
    float4 w10 = *(const float4*)wp1, w11 = *(const float4*)(wp1 + 4);
    n2a += dot4(a00) + dot4(a01);
    n2b += dot4(a10) + dot4(a11);
    __syncthreads();  // previous iteration's LDS frag reads done
    const int sw = 8 * (scb ^ (srow & 7));
    *(bf8_t*)&As[srow * 64 + sw] = conv8(a00, a01);
    *(bf8_t*)&As[(srow + 32) * 64 + sw] = conv8(a10, a11);
    *(bf8_t*)&Bs[srow * 64 + sw] = conv8(w00, w01);
    *(bf8_t*)&Bs[(srow + 32) * 64 + sw] = conv8(w10, w11);
    __syncthreads();
#pragma unroll
    for (int ks = 0; ks < 2; ++ks) {
      const int arow = w * 16 + lr;
      bf8_t af = *(const bf8_t*)&As[arow * 64 + 8 * ((ks * 4 + lg) ^ (arow & 7))];
#pragma unroll
      for (int nf = 0; nf < 4; ++nf) {
        const int brow = nf * 16 + lr;
        bf8_t bfr = *(const bf8_t*)&Bs[brow * 64 + 8 * ((ks * 4 + lg) ^ (brow & 7))];
        acc[nf] = __builtin_amdgcn_mfma_f32_16x16x32_bf16(af, bfr, acc[nf], 0, 0, 0);
      }
    }
  }
  // row logmap factors: reduce norm^2 over the 8 scb lanes (consecutive)
  n2a += __shfl_xor(n2a, 1, 64); n2a += __shfl_xor(n2a, 2, 64);
  n2a += __shfl_xor(n2a, 4, 64);
  n2b += __shfl_xor(n2b, 1, 64); n2b += __shfl_xor(n2b, 2, 64);
  n2b += __shfl_xor(n2b, 4, 64);
  if (scb == 0) {
    float na = fmaxf(sqrtf(n2a), EPSF), za = fminf(na, 1.0f - EPSF);
    facs[srow] = 0.34657359027997264f *
                 __builtin_amdgcn_logf((1.0f + za) / (1.0f - za)) / na;
    float nb = fmaxf(sqrtf(n2b), EPSF), zb = fminf(nb, 1.0f - EPSF);
    facs[srow + 32] = 0.34657359027997264f *
                      __builtin_amdgcn_logf((1.0f + zb) / (1.0f - zb)) / nb;
  }
  __syncthreads();
  float c[4][4];
#pragma unroll
  for (int nf = 0; nf < 4; ++nf) {
    const float bb = bias[j0 + nf * 16 + lr];
#pragma unroll
    for (int r = 0; r < 4; ++r)
      c[nf][r] = acc[nf][r] * facs[w * 16 + lg * 4 + r] + bb;
  }
  if (z < 2) {
    float part[4] = {0, 0, 0, 0};
#pragma unroll
    for (int nf = 0; nf < 4; ++nf)
#pragma unroll
      for (int r = 0; r < 4; ++r) part[r] += c[nf][r] * c[nf][r];
#pragma unroll
    for (int off = 1; off < 16; off <<= 1)
#pragma unroll
      for (int r = 0; r < 4; ++r) part[r] += __shfl_xor(part[r], off, 64);
    float fac[4];
#pragma unroll
    for (int r = 0; r < 4; ++r) {
      float n = fmaxf(sqrtf(part[r]), EPSF);
      fac[r] = fminf(tanh_pos(n), MAXN) / n;
    }
    u16 yb[4][4];
    float p2[4] = {0, 0, 0, 0};
#pragma unroll
    for (int nf = 0; nf < 4; ++nf)
#pragma unroll
      for (int r = 0; r < 4; ++r) {
        u16 t = f2bf(c[nf][r] * fac[r]);
        yb[nf][r] = t;
        float yf = bf2f(t);
        p2[r] += yf * yf;  // norm^2 of the rounded point
      }
#pragma unroll
    for (int off = 1; off < 16; off <<= 1)
#pragma unroll
      for (int r = 0; r < 4; ++r) p2[r] += __shfl_xor(p2[r], off, 64);
    u16* dst = z == 0 ? hq : hk;
    float* n2o = z == 0 ? qn2 : kn2;
#pragma unroll
    for (int nf = 0; nf < 4; ++nf)
#pragma unroll
      for (int r = 0; r < 4; ++r)
        dst[(size_t)(i0 + w * 16 + lg * 4 + r) * D + j0 + nf * 16 + lr] = yb[nf][r];
    if (lr == 0)
#pragma unroll
      for (int r = 0; r < 4; ++r)
        n2o[h * BS + i0 + w * 16 + lg * 4 + r] = p2[r];
  } else {
    // V: f16, transpose via LDS -> vT[(b*8+h)*64 + d][s]
    __syncthreads();
#pragma unroll
    for (int nf = 0; nf < 4; ++nf)
#pragma unroll
      for (int r = 0; r < 4; ++r) {
        const int prow = w * 16 + lg * 4 + r;  // local token s
        const int pcol = nf * 16 + lr;         // local d
        As[prow * 64 + 8 * ((pcol >> 3) ^ (prow & 7)) + (pcol & 7)] = f2h(c[nf][r]);
      }
    __syncthreads();
    const int d = tid >> 2, s0 = (tid & 3) * 16;
    const int b = i0 >> 9, sb = (i0 & 511) + s0;
    bf8_t o0, o1;
#pragma unroll
    for (int j = 0; j < 8; ++j) {
      const int s = s0 + j;
      o0[j] = (short)As[s * 64 + 8 * ((d >> 3) ^ (s & 7)) + (d & 7)];
    }
#pragma unroll
    for (int j = 0; j < 8; ++j) {
      const int s = s0 + 8 + j;
      o1[j] = (short)As[s * 64 + 8 * ((d >> 3) ^ (s & 7)) + (d & 7)];
    }
    u16* dst = vT + ((size_t)((b * 8 + h) * 64 + d)) * S + sb;
    *(bf8_t*)dst = o0;
    *(bf8_t*)(dst + 8) = o1;
  }
}

// ---------------- fused attention: 4 K-split waves per block, LDS combine --
// Wave w handles K-tiles 2w..2w+1 barrier-free (R12's per-wave code);
// partials land in the (reused) P-bounce LDS; one __syncthreads; block
// cooperatively sums 4 slices, normalizes, writes ctx bf16. No Opart.
__global__ __launch_bounds__(256) void fused_attn_blk(
    const u16* __restrict__ hq, const u16* __restrict__ hk,
    const u16* __restrict__ vT, const float* __restrict__ qn2,
    const float* __restrict__ kn2, u16* __restrict__ ctx) {
  const int bh = blockIdx.y, b = bh >> 3, h = bh & 7;
  const int i0 = blockIdx.x * 16;
  __shared__ __align__(16) u16 Ps[4][2][1024];  // per-wave P bounce (16 KB)
  __shared__ float rsL[4][16];
  const int tid = threadIdx.x;
  const int w = tid >> 6, l = tid & 63, lg = l >> 4, lr = l & 15;
  const int sp = w;  // this wave's K-split
  bf8_t qf[2];
#pragma unroll
  for (int ks = 0; ks < 2; ++ks)
    qf[ks] = *(const bf8_t*)(hq + (size_t)(b * S + i0 + lr) * D + h * 64 +
                             ks * 32 + lg * 8);
  float qq[4];
#pragma unroll
  for (int r = 0; r < 4; ++r) qq[r] = qn2[h * BS + b * S + i0 + lg * 4 + r];
  f4_t acc_o[4] = {{0, 0, 0, 0}, {0, 0, 0, 0}, {0, 0, 0, 0}, {0, 0, 0, 0}};
  float rloc[4] = {0, 0, 0, 0};
#pragma unroll
  for (int t = 0; t < 2; ++t) {
    const int kt = sp * 2 + t;
    const int kb = b * S + kt * 64;
    bf8_t kf[2][4], vf[2][4];
#pragma unroll
    for (int ks = 0; ks < 2; ++ks)
#pragma unroll
      for (int nf = 0; nf < 4; ++nf) {
        kf[ks][nf] = *(const bf8_t*)(hk + (size_t)(kb + nf * 16 + lr) * D +
                                     h * 64 + ks * 32 + lg * 8);
        vf[ks][nf] = *(const bf8_t*)(vT + (size_t)(bh * 64 + nf * 16 + lr) * S +
                                     kt * 64 + ks * 32 + lg * 8);
      }
    float kn[4];
#pragma unroll
    for (int nf = 0; nf < 4; ++nf) kn[nf] = kn2[h * BS + kb + nf * 16 + lr];
    f4_t sa[4] = {{0, 0, 0, 0}, {0, 0, 0, 0}, {0, 0, 0, 0}, {0, 0, 0, 0}};
#pragma unroll
    for (int ks = 0; ks < 2; ++ks)
#pragma unroll
      for (int nf = 0; nf < 4; ++nf)
        sa[nf] = __builtin_amdgcn_mfma_f32_16x16x32_bf16(qf[ks], kf[ks][nf],
                                                         sa[nf], 0, 0, 0);
    u16* Pb = Ps[w][t & 1];
    float ps[4] = {0, 0, 0, 0};
#pragma unroll
    for (int nf = 0; nf < 4; ++nf) {
      const float kk = kn[nf];
#pragma unroll
      for (int r = 0; r < 4; ++r) {
        const float tt = sa[nf][r];
        float num = fmaxf(qq[r] - 2.f * tt + kk, 0.f);
        float den = fmaxf(1.f - 2.f * tt + qq[r] * kk, EPSF);
        float rr = fminf(fmaxf(sqrtf(num / den), EPSF), MAXN);
        // p = ((1-r)/(1+r))^(1/8)
        float p = __builtin_amdgcn_exp2f(
            0.125f * __builtin_amdgcn_logf((1.f - rr) / (1.f + rr)));
        ps[r] += p;
        const int prow = lg * 4 + r, pcol = nf * 16 + lr;
        Pb[prow * 64 + 8 * ((pcol >> 3) ^ (prow & 7)) + (pcol & 7)] = f2h(p);
      }
    }
#pragma unroll
    for (int off = 1; off < 16; off <<= 1)
#pragma unroll
      for (int r = 0; r < 4; ++r) ps[r] += __shfl_xor(ps[r], off, 64);
#pragma unroll
    for (int r = 0; r < 4; ++r) rloc[r] += ps[r];
#pragma unroll
    for (int ks = 0; ks < 2; ++ks) {
      h8_t pa = *(const h8_t*)&Pb[lr * 64 + 8 * ((ks * 4 + lg) ^ (lr & 7))];
#pragma unroll
      for (int nf = 0; nf < 4; ++nf)
        acc_o[nf] = __builtin_amdgcn_mfma_f32_16x16x32_f16(pa, vf[ks][nf],
                                                           acc_o[nf], 0, 0, 0);
    }
  }
  // drop this wave's fp32 partial into its own (now-dead) P region
  float* myO = (float*)Ps + w * 1024;  // [16][64] floats == Ps[w] bytes
#pragma unroll
  for (int nf = 0; nf < 4; ++nf)
#pragma unroll
    for (int r = 0; r < 4; ++r)
      myO[(lg * 4 + r) * 64 + nf * 16 + lr] = acc_o[nf][r];
  if (lr == 0)
#pragma unroll
    for (int r = 0; r < 4; ++r) rsL[w][lg * 4 + r] = rloc[r];
  __syncthreads();
  // cooperative combine: 16 rows x 64 cols, 4 elems/thread
  const float* OsL = (const float*)Ps;
  const int row = tid >> 4, c4 = (tid & 15) * 4;
  const float rt = rsL[0][row] + rsL[1][row] + rsL[2][row] + rsL[3][row];
  const float inv = 1.f / rt;
  f4_t s = {0, 0, 0, 0};
#pragma unroll
  for (int sp2 = 0; sp2 < 4; ++sp2)
    s += *(const f4_t*)&OsL[sp2 * 1024 + row * 64 + c4];
  ushort4 o;
  o.x = f2bf(s[0] * inv); o.y = f2bf(s[1] * inv);
  o.z = f2bf(s[2] * inv); o.w = f2bf(s[3] * inv);
  *(ushort4*)&ctx[(size_t)(b * S + i0 + row) * D + h * 64 + c4] = o;
}

// ---------------- out projection: ctx(bf16) @ Wo^T(fp32->bf16) + bo --------
__global__ __launch_bounds__(256) void gemm_out_f(
    const u16* __restrict__ A, const float* __restrict__ Wo,
    const float* __restrict__ bias, float* __restrict__ C) {
  const int i0 = blockIdx.y * 64, j0 = blockIdx.x * 64;
  __shared__ __align__(16) u16 As[4096], Bs[4096];
  const int tid = threadIdx.x;
  const int w = tid >> 6, l = tid & 63, lg = l >> 4, lr = l & 15;
  const int srow = tid >> 3, scb = tid & 7;
  f4_t acc[4] = {{0, 0, 0, 0}, {0, 0, 0, 0}, {0, 0, 0, 0}, {0, 0, 0, 0}};
  for (int kt = 0; kt < D; kt += 64) {
    bf8_t a0 = *(const bf8_t*)(A + (size_t)(i0 + srow) * D + kt + scb * 8);
    bf8_t a1 = *(const bf8_t*)(A + (size_t)(i0 + srow + 32) * D + kt + scb * 8);
    const float* wp0 = Wo + (size_t)(j0 + srow) * D + kt + scb * 8;
    const float* wp1 = wp0 + (size_t)32 * D;
    float4 w00 = *(const float4*)wp0, w01 = *(const float4*)(wp0 + 4);
    float4 w10 = *(const float4*)wp1, w11 = *(const float4*)(wp1 + 4);
    __syncthreads();
    const int sw = 8 * (scb ^ (srow & 7));
    *(bf8_t*)&As[srow * 64 + sw] = a0;
    *(bf8_t*)&As[(srow + 32) * 64 + sw] = a1;
    *(bf8_t*)&Bs[srow * 64 + sw] = conv8(w00, w01);
    *(bf8_t*)&Bs[(srow + 32) * 64 + sw] = conv8(w10, w11);
    __syncthreads();
#pragma unroll
    for (int ks = 0; ks < 2; ++ks) {
      const int arow = w * 16 + lr;
      bf8_t af = *(const bf8_t*)&As[arow * 64 + 8 * ((ks * 4 + lg) ^ (arow & 7))];
#pragma unroll
      for (int nf = 0; nf < 4; ++nf) {
        const int brow = nf * 16 + lr;
        bf8_t bfr = *(const bf8_t*)&Bs[brow * 64 + 8 * ((ks * 4 + lg) ^ (brow & 7))];
        acc[nf] = __builtin_amdgcn_mfma_f32_16x16x32_bf16(af, bfr, acc[nf], 0, 0, 0);
      }
    }
  }
#pragma unroll
  for (int nf = 0; nf < 4; ++nf) {
    const int j = j0 + nf * 16 + lr;
    const float bb = bias[j];
#pragma unroll
    for (int r = 0; r < 4; ++r)
      C[(size_t)(i0 + w * 16 + lg * 4 + r) * D + j] = acc[nf][r] + bb;
  }
}

// ---------------- final expmap0 over full rows (512) -> d_out --------------
__global__ __launch_bounds__(256) void expmap_rows_full(
    const float* __restrict__ in, float* __restrict__ out) {
  const int row = blockIdx.x;
  const float2 xv = *(const float2*)(in + (size_t)row * D + threadIdx.x * 2);
  float s = xv.x * xv.x + xv.y * xv.y;
  __shared__ float sh[4];
  float ws = waveSum(s);
  if ((threadIdx.x & 63) == 0) sh[threadIdx.x >> 6] = ws;
  __syncthreads();
  float tot = sh[0] + sh[1] + sh[2] + sh[3];
  float n = fmaxf(sqrtf(tot), EPSF);
  float fac = fminf(tanh_pos(n), MAXN) / n;
  float2 o = make_float2(xv.x * fac, xv.y * fac);
  *(float2*)(out + (size_t)row * D + threadIdx.x * 2) = o;
}

}  // namespace

extern "C" void kernel_launch(void* const* d_in, const int* in_sizes, int n_in,
                              void* d_out, int out_size, void* d_ws,
                              size_t ws_size, hipStream_t stream) {
  const float* q = (const float*)d_in[0];
  const float* k = (const float*)d_in[1];
  const float* v = (const float*)d_in[2];
  const float* Wq = (const float*)d_in[3];
  const float* bq = (const float*)d_in[4];
  const float* Wk = (const float*)d_in[5];
  const float* bk = (const float*)d_in[6];
  const float* Wv = (const float*)d_in[7];
  const float* bv = (const float*)d_in[8];
  const float* Wo = (const float*)d_in[9];
  const float* bo = (const float*)d_in[10];
  float* out = (float*)d_out;

  char* w8 = (char*)d_ws;
  u16* hq = (u16*)(w8 + 0);                 // 1 MB
  u16* hk = (u16*)(w8 + 1048576);           // 1 MB
  u16* vT = (u16*)(w8 + 2097152);           // 1 MB  [bh*64+d][s] f16
  float* qn2 = (float*)(w8 + 3145728);      // 32 KB [H][BS]
  float* kn2 = (float*)(w8 + 3178496);      // 32 KB [H][BS]
  u16* ctx = (u16*)(w8 + 3211264);          // 1 MB  bf16
  float* olin = (float*)(w8 + 4259840);     // 2 MB  fp32

  gemm_qkv_f2<<<dim3(8, 16, 3), 256, 0, stream>>>(q, k, v, Wq, Wk, Wv, bq, bk,
                                                  bv, hq, hk, vT, qn2, kn2);
  fused_attn_blk<<<dim3(32, 16), 256, 0, stream>>>(hq, hk, vT, qn2, kn2, ctx);
  gemm_out_f<<<dim3(8, 16), 256, 0, stream>>>(ctx, Wo, bo, olin);
  expmap_rows_full<<<dim3(BS), 256, 0, stream>>>(olin, out);
}

// Round 15
// 39.026 us; speedup vs baseline: 1.6174x; 1.0718x over previous
//
#include <hip/hip_runtime.h>
#include <cmath>

#define DEV static __device__ __forceinline__

namespace {

constexpr int B = 2, S = 512, D = 512, H = 8;  // dh = 64
constexpr int BS = B * S;                      // 1024 token rows
constexpr float EPSF = 1e-5f;
constexpr float MAXN = 1.0f - 1e-3f;           // MAX_NORM / sqrt(c)

typedef unsigned short u16;
typedef unsigned int u32;
typedef __attribute__((ext_vector_type(8))) short bf8_t;    // bf16x8 (16B)
typedef __attribute__((ext_vector_type(8))) _Float16 h8_t;  // f16x8
typedef __attribute__((ext_vector_type(4))) float f4_t;

DEV float waveSum(float v) {
#pragma unroll
  for (int o = 32; o > 0; o >>= 1) v += __shfl_xor(v, o, 64);
  return v;
}
DEV u16 f2bf(float f) {  // RNE bf16
  u32 x = __float_as_uint(f);
  u32 r = x + 0x7fffu + ((x >> 16) & 1u);
  return (u16)(r >> 16);
}
DEV float bf2f(u16 u) { return __uint_as_float(((u32)u) << 16); }
DEV u16 f2h(float f) {
  _Float16 h = (_Float16)f;
  u16 u;
  __builtin_memcpy(&u, &h, 2);
  return u;
}
DEV float tanh_pos(float n) {  // tanh for n >= 0
  float e = __builtin_amdgcn_exp2f(2.8853900817779268f * n);  // e^(2n)
  return (e - 1.f) / (e + 1.f);
}
DEV bf8_t conv8(float4 a, float4 b) {
  bf8_t o;
  o[0] = (short)f2bf(a.x); o[1] = (short)f2bf(a.y);
  o[2] = (short)f2bf(a.z); o[3] = (short)f2bf(a.w);
  o[4] = (short)f2bf(b.x); o[5] = (short)f2bf(b.y);
  o[6] = (short)f2bf(b.z); o[7] = (short)f2bf(b.w);
  return o;
}
DEV float dot4(float4 a) { return a.x * a.x + a.y * a.y + a.z * a.z + a.w * a.w; }

// ---------------- QKV GEMM, logmap applied post-GEMM (linearity) -----------
// z=0: q -> hq bf16 + qn2 ; z=1: k -> hk + kn2 ; z=2: v -> vT f16, and each
// z=2 block also converts its 2048-element slice of Wo fp32 -> bf16 (wobf).
__global__ __launch_bounds__(256) void gemm_qkv_f2(
    const float* __restrict__ q, const float* __restrict__ k,
    const float* __restrict__ v, const float* __restrict__ Wq,
    const float* __restrict__ Wk, const float* __restrict__ Wv,
    const float* __restrict__ Wo, const float* __restrict__ bq,
    const float* __restrict__ bk, const float* __restrict__ bv,
    u16* __restrict__ hq, u16* __restrict__ hk, u16* __restrict__ vT,
    float* __restrict__ qn2, float* __restrict__ kn2,
    u16* __restrict__ wobf) {
  const int z = blockIdx.z;
  const float* A = z == 0 ? q : (z == 1 ? k : v);
  const float* W = z == 0 ? Wq : (z == 1 ? Wk : Wv);
  const float* bias = z == 0 ? bq : (z == 1 ? bk : bv);
  const int i0 = blockIdx.y * 64, j0 = blockIdx.x * 64, h = blockIdx.x;
  __shared__ __align__(16) u16 As[4096], Bs[4096];
  __shared__ float facs[64];
  const int tid = threadIdx.x;
  const int w = tid >> 6, l = tid & 63, lg = l >> 4, lr = l & 15;
  const int srow = tid >> 3, scb = tid & 7;
  if (z == 2) {  // side job: Wo fp32 -> bf16 (no LDS, no barrier interaction)
    const int bid = blockIdx.y * 8 + blockIdx.x;  // 0..127
    const int off = bid * 2048 + tid * 8;
    float4 wa = *(const float4*)(Wo + off);
    float4 wb = *(const float4*)(Wo + off + 4);
    *(bf8_t*)(wobf + off) = conv8(wa, wb);
  }
  f4_t acc[4] = {{0, 0, 0, 0}, {0, 0, 0, 0}, {0, 0, 0, 0}, {0, 0, 0, 0}};
  float n2a = 0.f, n2b = 0.f;  // row-norm^2 partials (this thread's 8 cols)
  for (int kt = 0; kt < D; kt += 64) {
    const float* ap0 = A + (size_t)(i0 + srow) * D + kt + scb * 8;
    const float* ap1 = ap0 + (size_t)32 * D;
    const float* wp0 = W + (size_t)(j0 + srow) * D + kt + scb * 8;
    const float* wp1 = wp0 + (size_t)32 * D;
    float4 a00 = *(const float4*)ap0, a01 = *(const float4*)(ap0 + 4);
    float4 a10 = *(const float4*)ap1, a11 = *(const float4*)(ap1 + 4);
    float4 w00 = *(const float4*)wp0, w01 = *(const float4*)(wp0 + 4);
    float4 w10 = *(const float4*)wp1, w11 = *(const float4*)(wp1 + 4);
    n2a += dot4(a00) + dot4(a01);
    n2b += dot4(a10) + dot4(a11);
    __syncthreads();  // previous iteration's LDS frag reads done
    const int sw = 8 * (scb ^ (srow & 7));
    *(bf8_t*)&As[srow * 64 + sw] = conv8(a00, a01);
    *(bf8_t*)&As[(srow + 32) * 64 + sw] = conv8(a10, a11);
    *(bf8_t*)&Bs[srow * 64 + sw] = conv8(w00, w01);
    *(bf8_t*)&Bs[(srow + 32) * 64 + sw] = conv8(w10, w11);
    __syncthreads();
#pragma unroll
    for (int ks = 0; ks < 2; ++ks) {
      const int arow = w * 16 + lr;
      bf8_t af = *(const bf8_t*)&As[arow * 64 + 8 * ((ks * 4 + lg) ^ (arow & 7))];
#pragma unroll
      for (int nf = 0; nf < 4; ++nf) {
        const int brow = nf * 16 + lr;
        bf8_t bfr = *(const bf8_t*)&Bs[brow * 64 + 8 * ((ks * 4 + lg) ^ (brow & 7))];
        acc[nf] = __builtin_amdgcn_mfma_f32_16x16x32_bf16(af, bfr, acc[nf], 0, 0, 0);
      }
    }
  }
  // row logmap factors: reduce norm^2 over the 8 scb lanes (consecutive)
  n2a += __shfl_xor(n2a, 1, 64); n2a += __shfl_xor(n2a, 2, 64);
  n2a += __shfl_xor(n2a, 4, 64);
  n2b += __shfl_xor(n2b, 1, 64); n2b += __shfl_xor(n2b, 2, 64);
  n2b += __shfl_xor(n2b, 4, 64);
  if (scb == 0) {
    float na = fmaxf(sqrtf(n2a), EPSF), za = fminf(na, 1.0f - EPSF);
    facs[srow] = 0.34657359027997264f *
                 __builtin_amdgcn_logf((1.0f + za) / (1.0f - za)) / na;
    float nb = fmaxf(sqrtf(n2b), EPSF), zb = fminf(nb, 1.0f - EPSF);
    facs[srow + 32] = 0.34657359027997264f *
                      __builtin_amdgcn_logf((1.0f + zb) / (1.0f - zb)) / nb;
  }
  __syncthreads();
  float c[4][4];
#pragma unroll
  for (int nf = 0; nf < 4; ++nf) {
    const float bb = bias[j0 + nf * 16 + lr];
#pragma unroll
    for (int r = 0; r < 4; ++r)
      c[nf][r] = acc[nf][r] * facs[w * 16 + lg * 4 + r] + bb;
  }
  if (z < 2) {
    float part[4] = {0, 0, 0, 0};
#pragma unroll
    for (int nf = 0; nf < 4; ++nf)
#pragma unroll
      for (int r = 0; r < 4; ++r) part[r] += c[nf][r] * c[nf][r];
#pragma unroll
    for (int off = 1; off < 16; off <<= 1)
#pragma unroll
      for (int r = 0; r < 4; ++r) part[r] += __shfl_xor(part[r], off, 64);
    float fac[4];
#pragma unroll
    for (int r = 0; r < 4; ++r) {
      float n = fmaxf(sqrtf(part[r]), EPSF);
      fac[r] = fminf(tanh_pos(n), MAXN) / n;
    }
    u16 yb[4][4];
    float p2[4] = {0, 0, 0, 0};
#pragma unroll
    for (int nf = 0; nf < 4; ++nf)
#pragma unroll
      for (int r = 0; r < 4; ++r) {
        u16 t = f2bf(c[nf][r] * fac[r]);
        yb[nf][r] = t;
        float yf = bf2f(t);
        p2[r] += yf * yf;  // norm^2 of the rounded point
      }
#pragma unroll
    for (int off = 1; off < 16; off <<= 1)
#pragma unroll
      for (int r = 0; r < 4; ++r) p2[r] += __shfl_xor(p2[r], off, 64);
    u16* dst = z == 0 ? hq : hk;
    float* n2o = z == 0 ? qn2 : kn2;
#pragma unroll
    for (int nf = 0; nf < 4; ++nf)
#pragma unroll
      for (int r = 0; r < 4; ++r)
        dst[(size_t)(i0 + w * 16 + lg * 4 + r) * D + j0 + nf * 16 + lr] = yb[nf][r];
    if (lr == 0)
#pragma unroll
      for (int r = 0; r < 4; ++r)
        n2o[h * BS + i0 + w * 16 + lg * 4 + r] = p2[r];
  } else {
    // V: f16, transpose via LDS -> vT[(b*8+h)*64 + d][s]
    __syncthreads();
#pragma unroll
    for (int nf = 0; nf < 4; ++nf)
#pragma unroll
      for (int r = 0; r < 4; ++r) {
        const int prow = w * 16 + lg * 4 + r;  // local token s
        const int pcol = nf * 16 + lr;         // local d
        As[prow * 64 + 8 * ((pcol >> 3) ^ (prow & 7)) + (pcol & 7)] = f2h(c[nf][r]);
      }
    __syncthreads();
    const int d = tid >> 2, s0 = (tid & 3) * 16;
    const int b = i0 >> 9, sb = (i0 & 511) + s0;
    bf8_t o0, o1;
#pragma unroll
    for (int j = 0; j < 8; ++j) {
      const int s = s0 + j;
      o0[j] = (short)As[s * 64 + 8 * ((d >> 3) ^ (s & 7)) + (d & 7)];
    }
#pragma unroll
    for (int j = 0; j < 8; ++j) {
      const int s = s0 + 8 + j;
      o1[j] = (short)As[s * 64 + 8 * ((d >> 3) ^ (s & 7)) + (d & 7)];
    }
    u16* dst = vT + ((size_t)((b * 8 + h) * 64 + d)) * S + sb;
    *(bf8_t*)dst = o0;
    *(bf8_t*)(dst + 8) = o1;
  }
}

// ---------------- fused attention: 4 K-split waves per block, LDS combine --
__global__ __launch_bounds__(256) void fused_attn_blk(
    const u16* __restrict__ hq, const u16* __restrict__ hk,
    const u16* __restrict__ vT, const float* __restrict__ qn2,
    const float* __restrict__ kn2, u16* __restrict__ ctx) {
  const int bh = blockIdx.y, b = bh >> 3, h = bh & 7;
  const int i0 = blockIdx.x * 16;
  __shared__ __align__(16) u16 Ps[4][2][1024];  // per-wave P bounce (16 KB)
  __shared__ float rsL[4][16];
  const int tid = threadIdx.x;
  const int w = tid >> 6, l = tid & 63, lg = l >> 4, lr = l & 15;
  const int sp = w;  // this wave's K-split
  bf8_t qf[2];
#pragma unroll
  for (int ks = 0; ks < 2; ++ks)
    qf[ks] = *(const bf8_t*)(hq + (size_t)(b * S + i0 + lr) * D + h * 64 +
                             ks * 32 + lg * 8);
  float qq[4];
#pragma unroll
  for (int r = 0; r < 4; ++r) qq[r] = qn2[h * BS + b * S + i0 + lg * 4 + r];
  f4_t acc_o[4] = {{0, 0, 0, 0}, {0, 0, 0, 0}, {0, 0, 0, 0}, {0, 0, 0, 0}};
  float rloc[4] = {0, 0, 0, 0};
#pragma unroll
  for (int t = 0; t < 2; ++t) {
    const int kt = sp * 2 + t;
    const int kb = b * S + kt * 64;
    bf8_t kf[2][4], vf[2][4];
#pragma unroll
    for (int ks = 0; ks < 2; ++ks)
#pragma unroll
      for (int nf = 0; nf < 4; ++nf) {
        kf[ks][nf] = *(const bf8_t*)(hk + (size_t)(kb + nf * 16 + lr) * D +
                                     h * 64 + ks * 32 + lg * 8);
        vf[ks][nf] = *(const bf8_t*)(vT + (size_t)(bh * 64 + nf * 16 + lr) * S +
                                     kt * 64 + ks * 32 + lg * 8);
      }
    float kn[4];
#pragma unroll
    for (int nf = 0; nf < 4; ++nf) kn[nf] = kn2[h * BS + kb + nf * 16 + lr];
    f4_t sa[4] = {{0, 0, 0, 0}, {0, 0, 0, 0}, {0, 0, 0, 0}, {0, 0, 0, 0}};
#pragma unroll
    for (int ks = 0; ks < 2; ++ks)
#pragma unroll
      for (int nf = 0; nf < 4; ++nf)
        sa[nf] = __builtin_amdgcn_mfma_f32_16x16x32_bf16(qf[ks], kf[ks][nf],
                                                         sa[nf], 0, 0, 0);
    u16* Pb = Ps[w][t & 1];
    float ps[4] = {0, 0, 0, 0};
#pragma unroll
    for (int nf = 0; nf < 4; ++nf) {
      const float kk = kn[nf];
#pragma unroll
      for (int r = 0; r < 4; ++r) {
        const float tt = sa[nf][r];
        float num = fmaxf(qq[r] - 2.f * tt + kk, 0.f);
        float den = fmaxf(1.f - 2.f * tt + qq[r] * kk, EPSF);
        float rr = fminf(fmaxf(sqrtf(num / den), EPSF), MAXN);
        // p = ((1-r)/(1+r))^(1/8)
        float p = __builtin_amdgcn_exp2f(
            0.125f * __builtin_amdgcn_logf((1.f - rr) / (1.f + rr)));
        ps[r] += p;
        const int prow = lg * 4 + r, pcol = nf * 16 + lr;
        Pb[prow * 64 + 8 * ((pcol >> 3) ^ (prow & 7)) + (pcol & 7)] = f2h(p);
      }
    }
#pragma unroll
    for (int off = 1; off < 16; off <<= 1)
#pragma unroll
      for (int r = 0; r < 4; ++r) ps[r] += __shfl_xor(ps[r], off, 64);
#pragma unroll
    for (int r = 0; r < 4; ++r) rloc[r] += ps[r];
#pragma unroll
    for (int ks = 0; ks < 2; ++ks) {
      h8_t pa = *(const h8_t*)&Pb[lr * 64 + 8 * ((ks * 4 + lg) ^ (lr & 7))];
#pragma unroll
      for (int nf = 0; nf < 4; ++nf)
        acc_o[nf] = __builtin_amdgcn_mfma_f32_16x16x32_f16(pa, vf[ks][nf],
                                                           acc_o[nf], 0, 0, 0);
    }
  }
  // drop this wave's fp32 partial into its own (now-dead) P region
  float* myO = (float*)Ps + w * 1024;  // [16][64] floats == Ps[w] bytes
#pragma unroll
  for (int nf = 0; nf < 4; ++nf)
#pragma unroll
    for (int r = 0; r < 4; ++r)
      myO[(lg * 4 + r) * 64 + nf * 16 + lr] = acc_o[nf][r];
  if (lr == 0)
#pragma unroll
    for (int r = 0; r < 4; ++r) rsL[w][lg * 4 + r] = rloc[r];
  __syncthreads();
  // cooperative combine: 16 rows x 64 cols, 4 elems/thread
  const float* OsL = (const float*)Ps;
  const int row = tid >> 4, c4 = (tid & 15) * 4;
  const float rt = rsL[0][row] + rsL[1][row] + rsL[2][row] + rsL[3][row];
  const float inv = 1.f / rt;
  f4_t s = {0, 0, 0, 0};
#pragma unroll
  for (int sp2 = 0; sp2 < 4; ++sp2)
    s += *(const f4_t*)&OsL[sp2 * 1024 + row * 64 + c4];
  ushort4 o;
  o.x = f2bf(s[0] * inv); o.y = f2bf(s[1] * inv);
  o.z = f2bf(s[2] * inv); o.w = f2bf(s[3] * inv);
  *(ushort4*)&ctx[(size_t)(b * S + i0 + row) * D + h * 64 + c4] = o;
}

// ---------------- out projection: ctx(bf16) @ WoBf^T + bo, 32x64 tiles -----
// Grid 8 x 32 = 256 blocks (1/CU) for 2x the occupancy of 64x64 tiling.
__global__ __launch_bounds__(256) void gemm_out_b(
    const u16* __restrict__ A, const u16* __restrict__ Wob,
    const float* __restrict__ bias, float* __restrict__ C) {
  const int i0 = blockIdx.y * 32, j0 = blockIdx.x * 64;
  __shared__ __align__(16) u16 As[2048], Bs[4096];
  const int tid = threadIdx.x;
  const int w = tid >> 6, l = tid & 63, lg = l >> 4, lr = l & 15;
  const int srow = tid >> 3, scb = tid & 7;  // srow 0..31
  const int mrow = (w >> 1) * 16, ncol = (w & 1) * 32;
  f4_t acc[2] = {{0, 0, 0, 0}, {0, 0, 0, 0}};
  for (int kt = 0; kt < D; kt += 64) {
    bf8_t a0 = *(const bf8_t*)(A + (size_t)(i0 + srow) * D + kt + scb * 8);
    bf8_t w0 = *(const bf8_t*)(Wob + (size_t)(j0 + srow) * D + kt + scb * 8);
    bf8_t w1 = *(const bf8_t*)(Wob + (size_t)(j0 + srow + 32) * D + kt + scb * 8);
    __syncthreads();
    const int sw = 8 * (scb ^ (srow & 7));
    *(bf8_t*)&As[srow * 64 + sw] = a0;
    *(bf8_t*)&Bs[srow * 64 + sw] = w0;
    *(bf8_t*)&Bs[(srow + 32) * 64 + sw] = w1;
    __syncthreads();
#pragma unroll
    for (int ks = 0; ks < 2; ++ks) {
      const int arow = mrow + lr;
      bf8_t af = *(const bf8_t*)&As[arow * 64 + 8 * ((ks * 4 + lg) ^ (arow & 7))];
#pragma unroll
      for (int nf = 0; nf < 2; ++nf) {
        const int brow = ncol + nf * 16 + lr;
        bf8_t bfr = *(const bf8_t*)&Bs[brow * 64 + 8 * ((ks * 4 + lg) ^ (brow & 7))];
        acc[nf] = __builtin_amdgcn_mfma_f32_16x16x32_bf16(af, bfr, acc[nf], 0, 0, 0);
      }
    }
  }
#pragma unroll
  for (int nf = 0; nf < 2; ++nf) {
    const int j = j0 + ncol + nf * 16 + lr;
    const float bb = bias[j];
#pragma unroll
    for (int r = 0; r < 4; ++r)
      C[(size_t)(i0 + mrow + lg * 4 + r) * D + j] = acc[nf][r] + bb;
  }
}

// ---------------- final expmap0 over full rows (512) -> d_out --------------
__global__ __launch_bounds__(256) void expmap_rows_full(
    const float* __restrict__ in, float* __restrict__ out) {
  const int row = blockIdx.x;
  const float2 xv = *(const float2*)(in + (size_t)row * D + threadIdx.x * 2);
  float s = xv.x * xv.x + xv.y * xv.y;
  __shared__ float sh[4];
  float ws = waveSum(s);
  if ((threadIdx.x & 63) == 0) sh[threadIdx.x >> 6] = ws;
  __syncthreads();
  float tot = sh[0] + sh[1] + sh[2] + sh[3];
  float n = fmaxf(sqrtf(tot), EPSF);
  float fac = fminf(tanh_pos(n), MAXN) / n;
  float2 o = make_float2(xv.x * fac, xv.y * fac);
  *(float2*)(out + (size_t)row * D + threadIdx.x * 2) = o;
}

}  // namespace

extern "C" void kernel_launch(void* const* d_in, const int* in_sizes, int n_in,
                              void* d_out, int out_size, void* d_ws,
                              size_t ws_size, hipStream_t stream) {
  const float* q = (const float*)d_in[0];
  const float* k = (const float*)d_in[1];
  const float* v = (const float*)d_in[2];
  const float* Wq = (const float*)d_in[3];
  const float* bq = (const float*)d_in[4];
  const float* Wk = (const float*)d_in[5];
  const float* bk = (const float*)d_in[6];
  const float* Wv = (const float*)d_in[7];
  const float* bv = (const float*)d_in[8];
  const float* Wo = (const float*)d_in[9];
  const float* bo = (const float*)d_in[10];
  float* out = (float*)d_out;

  char* w8 = (char*)d_ws;
  u16* hq = (u16*)(w8 + 0);                 // 1 MB
  u16* hk = (u16*)(w8 + 1048576);           // 1 MB
  u16* vT = (u16*)(w8 + 2097152);           // 1 MB  [bh*64+d][s] f16
  float* qn2 = (float*)(w8 + 3145728);      // 32 KB [H][BS]
  float* kn2 = (float*)(w8 + 3178496);      // 32 KB [H][BS]
  u16* ctx = (u16*)(w8 + 3211264);          // 1 MB  bf16
  float* olin = (float*)(w8 + 4259840);     // 2 MB  fp32
  u16* wobf = (u16*)(w8 + 6357000 + 504);   // 512 KB bf16 Wo (16B-aligned)
  wobf = (u16*)(w8 + 6357504);

  gemm_qkv_f2<<<dim3(8, 16, 3), 256, 0, stream>>>(
      q, k, v, Wq, Wk, Wv, Wo, bq, bk, bv, hq, hk, vT, qn2, kn2, wobf);
  fused_attn_blk<<<dim3(32, 16), 256, 0, stream>>>(hq, hk, vT, qn2, kn2, ctx);
  gemm_out_b<<<dim3(8, 32), 256, 0, stream>>>(ctx, wobf, bo, olin);
  expmap_rows_full<<<dim3(BS), 256, 0, stream>>>(olin, out);
}

// Round 16
// 38.744 us; speedup vs baseline: 1.6291x; 1.0073x over previous
//
#include <hip/hip_runtime.h>
#include <hip/hip_bf16.h>
#include <cmath>

#define DEV static __device__ __forceinline__

namespace {

constexpr int B = 2, S = 512, D = 512, H = 8;  // dh = 64
constexpr int BS = B * S;                      // 1024 token rows
constexpr float EPSF = 1e-5f;
constexpr float MAXN = 1.0f - 1e-3f;           // MAX_NORM / sqrt(c)

typedef unsigned short u16;
typedef unsigned int u32;
typedef __attribute__((ext_vector_type(8))) short bf8_t;    // bf16x8 (16B)
typedef __attribute__((ext_vector_type(8))) _Float16 h8_t;  // f16x8
typedef __attribute__((ext_vector_type(4))) float f4_t;

DEV float waveSum(float v) {
#pragma unroll
  for (int o = 32; o > 0; o >>= 1) v += __shfl_xor(v, o, 64);
  return v;
}
DEV u16 f2bf(float f) {  // RNE bf16 (scalar path; value needed back)
  u32 x = __float_as_uint(f);
  u32 r = x + 0x7fffu + ((x >> 16) & 1u);
  return (u16)(r >> 16);
}
DEV float bf2f(u16 u) { return __uint_as_float(((u32)u) << 16); }
DEV u16 f2h(float f) {
  _Float16 h = (_Float16)f;
  u16 u;
  __builtin_memcpy(&u, &h, 2);
  return u;
}
DEV float tanh_pos(float n) {  // tanh for n >= 0
  float e = __builtin_amdgcn_exp2f(2.8853900817779268f * n);  // e^(2n)
  return (e - 1.f) / (e + 1.f);
}
// hot-path pack: compiler lowers paired casts to v_cvt_pk_bf16_f32 (RNE)
DEV bf8_t conv8(float4 a, float4 b) {
  __hip_bfloat162 p[4] = {
      __float22bfloat162_rn(make_float2(a.x, a.y)),
      __float22bfloat162_rn(make_float2(a.z, a.w)),
      __float22bfloat162_rn(make_float2(b.x, b.y)),
      __float22bfloat162_rn(make_float2(b.z, b.w))};
  bf8_t o;
  __builtin_memcpy(&o, p, 16);
  return o;
}
DEV float dot4(float4 a) { return a.x * a.x + a.y * a.y + a.z * a.z + a.w * a.w; }

// ---------------- QKV GEMM, logmap applied post-GEMM (linearity) -----------
// z=0: q -> hq bf16 + qn2 ; z=1: k -> hk + kn2 ; z=2: v -> vT f16, and each
// z=2 block also converts its 2048-element slice of Wo fp32 -> bf16 (wobf).
__global__ __launch_bounds__(256) void gemm_qkv_f2(
    const float* __restrict__ q, const float* __restrict__ k,
    const float* __restrict__ v, const float* __restrict__ Wq,
    const float* __restrict__ Wk, const float* __restrict__ Wv,
    const float* __restrict__ Wo, const float* __restrict__ bq,
    const float* __restrict__ bk, const float* __restrict__ bv,
    u16* __restrict__ hq, u16* __restrict__ hk, u16* __restrict__ vT,
    float* __restrict__ qn2, float* __restrict__ kn2,
    u16* __restrict__ wobf) {
  const int z = blockIdx.z;
  const float* A = z == 0 ? q : (z == 1 ? k : v);
  const float* W = z == 0 ? Wq : (z == 1 ? Wk : Wv);
  const float* bias = z == 0 ? bq : (z == 1 ? bk : bv);
  const int i0 = blockIdx.y * 64, j0 = blockIdx.x * 64, h = blockIdx.x;
  __shared__ __align__(16) u16 As[4096], Bs[4096];
  __shared__ float facs[64];
  const int tid = threadIdx.x;
  const int w = tid >> 6, l = tid & 63, lg = l >> 4, lr = l & 15;
  const int srow = tid >> 3, scb = tid & 7;
  if (z == 2) {  // side job: Wo fp32 -> bf16 (no LDS, no barrier interaction)
    const int bid = blockIdx.y * 8 + blockIdx.x;  // 0..127
    const int off = bid * 2048 + tid * 8;
    float4 wa = *(const float4*)(Wo + off);
    float4 wb = *(const float4*)(Wo + off + 4);
    *(bf8_t*)(wobf + off) = conv8(wa, wb);
  }
  f4_t acc[4] = {{0, 0, 0, 0}, {0, 0, 0, 0}, {0, 0, 0, 0}, {0, 0, 0, 0}};
  float n2a = 0.f, n2b = 0.f;  // row-norm^2 partials (this thread's 8 cols)
  for (int kt = 0; kt < D; kt += 64) {
    const float* ap0 = A + (size_t)(i0 + srow) * D + kt + scb * 8;
    const float* ap1 = ap0 + (size_t)32 * D;
    const float* wp0 = W + (size_t)(j0 + srow) * D + kt + scb * 8;
    const float* wp1 = wp0 + (size_t)32 * D;
    float4 a00 = *(const float4*)ap0, a01 = *(const float4*)(ap0 + 4);
    float4 a10 = *(const float4*)ap1, a11 = *(const float4*)(ap1 + 4);
    float4 w00 = *(const float4*)wp0, w01 = *(const float4*)(wp0 + 4);
    float4 w10 = *(const float4*)wp1, w11 = *(const float4*)(wp1 + 4);
    n2a += dot4(a00) + dot4(a01);
    n2b += dot4(a10) + dot4(a11);
    __syncthreads();  // previous iteration's LDS frag reads done
    const int sw = 8 * (scb ^ (srow & 7));
    *(bf8_t*)&As[srow * 64 + sw] = conv8(a00, a01);
    *(bf8_t*)&As[(srow + 32) * 64 + sw] = conv8(a10, a11);
    *(bf8_t*)&Bs[srow * 64 + sw] = conv8(w00, w01);
    *(bf8_t*)&Bs[(srow + 32) * 64 + sw] = conv8(w10, w11);
    __syncthreads();
#pragma unroll
    for (int ks = 0; ks < 2; ++ks) {
      const int arow = w * 16 + lr;
      bf8_t af = *(const bf8_t*)&As[arow * 64 + 8 * ((ks * 4 + lg) ^ (arow & 7))];
#pragma unroll
      for (int nf = 0; nf < 4; ++nf) {
        const int brow = nf * 16 + lr;
        bf8_t bfr = *(const bf8_t*)&Bs[brow * 64 + 8 * ((ks * 4 + lg) ^ (brow & 7))];
        acc[nf] = __builtin_amdgcn_mfma_f32_16x16x32_bf16(af, bfr, acc[nf], 0, 0, 0);
      }
    }
  }
  // row logmap factors: reduce norm^2 over the 8 scb lanes (consecutive)
  n2a += __shfl_xor(n2a, 1, 64); n2a += __shfl_xor(n2a, 2, 64);
  n2a += __shfl_xor(n2a, 4, 64);
  n2b += __shfl_xor(n2b, 1, 64); n2b += __shfl_xor(n2b, 2, 64);
  n2b += __shfl_xor(n2b, 4, 64);
  if (scb == 0) {
    float na = fmaxf(sqrtf(n2a), EPSF), za = fminf(na, 1.0f - EPSF);
    facs[srow] = 0.34657359027997264f *
                 __builtin_amdgcn_logf((1.0f + za) / (1.0f - za)) / na;
    float nb = fmaxf(sqrtf(n2b), EPSF), zb = fminf(nb, 1.0f - EPSF);
    facs[srow + 32] = 0.34657359027997264f *
                      __builtin_amdgcn_logf((1.0f + zb) / (1.0f - zb)) / nb;
  }
  __syncthreads();
  float c[4][4];
#pragma unroll
  for (int nf = 0; nf < 4; ++nf) {
    const float bb = bias[j0 + nf * 16 + lr];
#pragma unroll
    for (int r = 0; r < 4; ++r)
      c[nf][r] = acc[nf][r] * facs[w * 16 + lg * 4 + r] + bb;
  }
  if (z < 2) {
    float part[4] = {0, 0, 0, 0};
#pragma unroll
    for (int nf = 0; nf < 4; ++nf)
#pragma unroll
      for (int r = 0; r < 4; ++r) part[r] += c[nf][r] * c[nf][r];
#pragma unroll
    for (int off = 1; off < 16; off <<= 1)
#pragma unroll
      for (int r = 0; r < 4; ++r) part[r] += __shfl_xor(part[r], off, 64);
    float fac[4];
#pragma unroll
    for (int r = 0; r < 4; ++r) {
      float n = fmaxf(sqrtf(part[r]), EPSF);
      fac[r] = fminf(tanh_pos(n), MAXN) / n;
    }
    u16 yb[4][4];
    float p2[4] = {0, 0, 0, 0};
#pragma unroll
    for (int nf = 0; nf < 4; ++nf)
#pragma unroll
      for (int r = 0; r < 4; ++r) {
        u16 t = f2bf(c[nf][r] * fac[r]);
        yb[nf][r] = t;
        float yf = bf2f(t);
        p2[r] += yf * yf;  // norm^2 of the rounded point
      }
#pragma unroll
    for (int off = 1; off < 16; off <<= 1)
#pragma unroll
      for (int r = 0; r < 4; ++r) p2[r] += __shfl_xor(p2[r], off, 64);
    u16* dst = z == 0 ? hq : hk;
    float* n2o = z == 0 ? qn2 : kn2;
#pragma unroll
    for (int nf = 0; nf < 4; ++nf)
#pragma unroll
      for (int r = 0; r < 4; ++r)
        dst[(size_t)(i0 + w * 16 + lg * 4 + r) * D + j0 + nf * 16 + lr] = yb[nf][r];
    if (lr == 0)
#pragma unroll
      for (int r = 0; r < 4; ++r)
        n2o[h * BS + i0 + w * 16 + lg * 4 + r] = p2[r];
  } else {
    // V: f16, transpose via LDS -> vT[(b*8+h)*64 + d][s]
    __syncthreads();
#pragma unroll
    for (int nf = 0; nf < 4; ++nf)
#pragma unroll
      for (int r = 0; r < 4; ++r) {
        const int prow = w * 16 + lg * 4 + r;  // local token s
        const int pcol = nf * 16 + lr;         // local d
        As[prow * 64 + 8 * ((pcol >> 3) ^ (prow & 7)) + (pcol & 7)] = f2h(c[nf][r]);
      }
    __syncthreads();
    const int d = tid >> 2, s0 = (tid & 3) * 16;
    const int b = i0 >> 9, sb = (i0 & 511) + s0;
    bf8_t o0, o1;
#pragma unroll
    for (int j = 0; j < 8; ++j) {
      const int s = s0 + j;
      o0[j] = (short)As[s * 64 + 8 * ((d >> 3) ^ (s & 7)) + (d & 7)];
    }
#pragma unroll
    for (int j = 0; j < 8; ++j) {
      const int s = s0 + 8 + j;
      o1[j] = (short)As[s * 64 + 8 * ((d >> 3) ^ (s & 7)) + (d & 7)];
    }
    u16* dst = vT + ((size_t)((b * 8 + h) * 64 + d)) * S + sb;
    *(bf8_t*)dst = o0;
    *(bf8_t*)(dst + 8) = o1;
  }
}

// ---------------- fused attention: 4 K-split waves per block, LDS combine --
__global__ __launch_bounds__(256) void fused_attn_blk(
    const u16* __restrict__ hq, const u16* __restrict__ hk,
    const u16* __restrict__ vT, const float* __restrict__ qn2,
    const float* __restrict__ kn2, u16* __restrict__ ctx) {
  const int bh = blockIdx.y, b = bh >> 3, h = bh & 7;
  const int i0 = blockIdx.x * 16;
  __shared__ __align__(16) u16 Ps[4][2][1024];  // per-wave P bounce (16 KB)
  __shared__ float rsL[4][16];
  const int tid = threadIdx.x;
  const int w = tid >> 6, l = tid & 63, lg = l >> 4, lr = l & 15;
  const int sp = w;  // this wave's K-split
  bf8_t qf[2];
#pragma unroll
  for (int ks = 0; ks < 2; ++ks)
    qf[ks] = *(const bf8_t*)(hq + (size_t)(b * S + i0 + lr) * D + h * 64 +
                             ks * 32 + lg * 8);
  float qq[4];
#pragma unroll
  for (int r = 0; r < 4; ++r) qq[r] = qn2[h * BS + b * S + i0 + lg * 4 + r];
  f4_t acc_o[4] = {{0, 0, 0, 0}, {0, 0, 0, 0}, {0, 0, 0, 0}, {0, 0, 0, 0}};
  float rloc[4] = {0, 0, 0, 0};
#pragma unroll
  for (int t = 0; t < 2; ++t) {
    const int kt = sp * 2 + t;
    const int kb = b * S + kt * 64;
    bf8_t kf[2][4], vf[2][4];
#pragma unroll
    for (int ks = 0; ks < 2; ++ks)
#pragma unroll
      for (int nf = 0; nf < 4; ++nf) {
        kf[ks][nf] = *(const bf8_t*)(hk + (size_t)(kb + nf * 16 + lr) * D +
                                     h * 64 + ks * 32 + lg * 8);
        vf[ks][nf] = *(const bf8_t*)(vT + (size_t)(bh * 64 + nf * 16 + lr) * S +
                                     kt * 64 + ks * 32 + lg * 8);
      }
    float kn[4];
#pragma unroll
    for (int nf = 0; nf < 4; ++nf) kn[nf] = kn2[h * BS + kb + nf * 16 + lr];
    f4_t sa[4] = {{0, 0, 0, 0}, {0, 0, 0, 0}, {0, 0, 0, 0}, {0, 0, 0, 0}};
#pragma unroll
    for (int ks = 0; ks < 2; ++ks)
#pragma unroll
      for (int nf = 0; nf < 4; ++nf)
        sa[nf] = __builtin_amdgcn_mfma_f32_16x16x32_bf16(qf[ks], kf[ks][nf],
                                                         sa[nf], 0, 0, 0);
    u16* Pb = Ps[w][t & 1];
    float ps[4] = {0, 0, 0, 0};
#pragma unroll
    for (int nf = 0; nf < 4; ++nf) {
      const float kk = kn[nf];
#pragma unroll
      for (int r = 0; r < 4; ++r) {
        const float tt = sa[nf][r];
        float num = fmaxf(qq[r] - 2.f * tt + kk, 0.f);
        float den = fmaxf(1.f - 2.f * tt + qq[r] * kk, EPSF);
        float rr = fminf(fmaxf(sqrtf(num / den), EPSF), MAXN);
        // p = ((1-r)/(1+r))^(1/8)
        float p = __builtin_amdgcn_exp2f(
            0.125f * __builtin_amdgcn_logf((1.f - rr) / (1.f + rr)));
        ps[r] += p;
        const int prow = lg * 4 + r, pcol = nf * 16 + lr;
        Pb[prow * 64 + 8 * ((pcol >> 3) ^ (prow & 7)) + (pcol & 7)] = f2h(p);
      }
    }
#pragma unroll
    for (int off = 1; off < 16; off <<= 1)
#pragma unroll
      for (int r = 0; r < 4; ++r) ps[r] += __shfl_xor(ps[r], off, 64);
#pragma unroll
    for (int r = 0; r < 4; ++r) rloc[r] += ps[r];
#pragma unroll
    for (int ks = 0; ks < 2; ++ks) {
      h8_t pa = *(const h8_t*)&Pb[lr * 64 + 8 * ((ks * 4 + lg) ^ (lr & 7))];
#pragma unroll
      for (int nf = 0; nf < 4; ++nf)
        acc_o[nf] = __builtin_amdgcn_mfma_f32_16x16x32_f16(pa, vf[ks][nf],
                                                           acc_o[nf], 0, 0, 0);
    }
  }
  // drop this wave's fp32 partial into its own (now-dead) P region
  float* myO = (float*)Ps + w * 1024;  // [16][64] floats == Ps[w] bytes
#pragma unroll
  for (int nf = 0; nf < 4; ++nf)
#pragma unroll
    for (int r = 0; r < 4; ++r)
      myO[(lg * 4 + r) * 64 + nf * 16 + lr] = acc_o[nf][r];
  if (lr == 0)
#pragma unroll
    for (int r = 0; r < 4; ++r) rsL[w][lg * 4 + r] = rloc[r];
  __syncthreads();
  // cooperative combine: 16 rows x 64 cols, 4 elems/thread
  const float* OsL = (const float*)Ps;
  const int row = tid >> 4, c4 = (tid & 15) * 4;
  const float rt = rsL[0][row] + rsL[1][row] + rsL[2][row] + rsL[3][row];
  const float inv = 1.f / rt;
  f4_t s = {0, 0, 0, 0};
#pragma unroll
  for (int sp2 = 0; sp2 < 4; ++sp2)
    s += *(const f4_t*)&OsL[sp2 * 1024 + row * 64 + c4];
  __hip_bfloat162 p[2] = {
      __float22bfloat162_rn(make_float2(s[0] * inv, s[1] * inv)),
      __float22bfloat162_rn(make_float2(s[2] * inv, s[3] * inv))};
  ushort4 o;
  __builtin_memcpy(&o, p, 8);
  *(ushort4*)&ctx[(size_t)(b * S + i0 + row) * D + h * 64 + c4] = o;
}

// ---------------- out projection: ctx(bf16) @ WoBf^T + bo, 32x64 tiles -----
// Grid 8 x 32 = 256 blocks (1/CU) for 2x the occupancy of 64x64 tiling.
__global__ __launch_bounds__(256) void gemm_out_b(
    const u16* __restrict__ A, const u16* __restrict__ Wob,
    const float* __restrict__ bias, float* __restrict__ C) {
  const int i0 = blockIdx.y * 32, j0 = blockIdx.x * 64;
  __shared__ __align__(16) u16 As[2048], Bs[4096];
  const int tid = threadIdx.x;
  const int w = tid >> 6, l = tid & 63, lg = l >> 4, lr = l & 15;
  const int srow = tid >> 3, scb = tid & 7;  // srow 0..31
  const int mrow = (w >> 1) * 16, ncol = (w & 1) * 32;
  f4_t acc[2] = {{0, 0, 0, 0}, {0, 0, 0, 0}};
  for (int kt = 0; kt < D; kt += 64) {
    bf8_t a0 = *(const bf8_t*)(A + (size_t)(i0 + srow) * D + kt + scb * 8);
    bf8_t w0 = *(const bf8_t*)(Wob + (size_t)(j0 + srow) * D + kt + scb * 8);
    bf8_t w1 = *(const bf8_t*)(Wob + (size_t)(j0 + srow + 32) * D + kt + scb * 8);
    __syncthreads();
    const int sw = 8 * (scb ^ (srow & 7));
    *(bf8_t*)&As[srow * 64 + sw] = a0;
    *(bf8_t*)&Bs[srow * 64 + sw] = w0;
    *(bf8_t*)&Bs[(srow + 32) * 64 + sw] = w1;
    __syncthreads();
#pragma unroll
    for (int ks = 0; ks < 2; ++ks) {
      const int arow = mrow + lr;
      bf8_t af = *(const bf8_t*)&As[arow * 64 + 8 * ((ks * 4 + lg) ^ (arow & 7))];
#pragma unroll
      for (int nf = 0; nf < 2; ++nf) {
        const int brow = ncol + nf * 16 + lr;
        bf8_t bfr = *(const bf8_t*)&Bs[brow * 64 + 8 * ((ks * 4 + lg) ^ (brow & 7))];
        acc[nf] = __builtin_amdgcn_mfma_f32_16x16x32_bf16(af, bfr, acc[nf], 0, 0, 0);
      }
    }
  }
#pragma unroll
  for (int nf = 0; nf < 2; ++nf) {
    const int j = j0 + ncol + nf * 16 + lr;
    const float bb = bias[j];
#pragma unroll
    for (int r = 0; r < 4; ++r)
      C[(size_t)(i0 + mrow + lg * 4 + r) * D + j] = acc[nf][r] + bb;
  }
}

// ---------------- final expmap0 over full rows (512) -> d_out --------------
__global__ __launch_bounds__(256) void expmap_rows_full(
    const float* __restrict__ in, float* __restrict__ out) {
  const int row = blockIdx.x;
  const float2 xv = *(const float2*)(in + (size_t)row * D + threadIdx.x * 2);
  float s = xv.x * xv.x + xv.y * xv.y;
  __shared__ float sh[4];
  float ws = waveSum(s);
  if ((threadIdx.x & 63) == 0) sh[threadIdx.x >> 6] = ws;
  __syncthreads();
  float tot = sh[0] + sh[1] + sh[2] + sh[3];
  float n = fmaxf(sqrtf(tot), EPSF);
  float fac = fminf(tanh_pos(n), MAXN) / n;
  float2 o = make_float2(xv.x * fac, xv.y * fac);
  *(float2*)(out + (size_t)row * D + threadIdx.x * 2) = o;
}

}  // namespace

extern "C" void kernel_launch(void* const* d_in, const int* in_sizes, int n_in,
                              void* d_out, int out_size, void* d_ws,
                              size_t ws_size, hipStream_t stream) {
  const float* q = (const float*)d_in[0];
  const float* k = (const float*)d_in[1];
  const float* v = (const float*)d_in[2];
  const float* Wq = (const float*)d_in[3];
  const float* bq = (const float*)d_in[4];
  const float* Wk = (const float*)d_in[5];
  const float* bk = (const float*)d_in[6];
  const float* Wv = (const float*)d_in[7];
  const float* bv = (const float*)d_in[8];
  const float* Wo = (const float*)d_in[9];
  const float* bo = (const float*)d_in[10];
  float* out = (float*)d_out;

  char* w8 = (char*)d_ws;
  u16* hq = (u16*)(w8 + 0);                 // 1 MB
  u16* hk = (u16*)(w8 + 1048576);           // 1 MB
  u16* vT = (u16*)(w8 + 2097152);           // 1 MB  [bh*64+d][s] f16
  float* qn2 = (float*)(w8 + 3145728);      // 32 KB [H][BS]
  float* kn2 = (float*)(w8 + 3178496);      // 32 KB [H][BS]
  u16* ctx = (u16*)(w8 + 3211264);          // 1 MB  bf16
  float* olin = (float*)(w8 + 4259840);     // 2 MB  fp32
  u16* wobf = (u16*)(w8 + 6357504);         // 512 KB bf16 Wo

  gemm_qkv_f2<<<dim3(8, 16, 3), 256, 0, stream>>>(
      q, k, v, Wq, Wk, Wv, Wo, bq, bk, bv, hq, hk, vT, qn2, kn2, wobf);
  fused_attn_blk<<<dim3(32, 16), 256, 0, stream>>>(hq, hk, vT, qn2, kn2, ctx);
  gemm_out_b<<<dim3(8, 32), 256, 0, stream>>>(ctx, wobf, bo, olin);
  expmap_rows_full<<<dim3(BS), 256, 0, stream>>>(olin, out);
}

// Round 17
// 38.507 us; speedup vs baseline: 1.6392x; 1.0061x over previous
//
#include <hip/hip_runtime.h>
#include <hip/hip_bf16.h>
#include <cmath>

#define DEV static __device__ __forceinline__

namespace {

constexpr int B = 2, S = 512, D = 512, H = 8;  // dh = 64
constexpr int BS = B * S;                      // 1024 token rows
constexpr float EPSF = 1e-5f;
constexpr float MAXN = 1.0f - 1e-3f;           // MAX_NORM / sqrt(c)

typedef unsigned short u16;
typedef unsigned int u32;
typedef __attribute__((ext_vector_type(8))) short bf8_t;    // bf16x8 (16B)
typedef __attribute__((ext_vector_type(8))) _Float16 h8_t;  // f16x8
typedef __attribute__((ext_vector_type(4))) float f4_t;

DEV float waveSum(float v) {
#pragma unroll
  for (int o = 32; o > 0; o >>= 1) v += __shfl_xor(v, o, 64);
  return v;
}
DEV u16 f2bf(float f) {  // RNE bf16 (scalar path; value needed back)
  u32 x = __float_as_uint(f);
  u32 r = x + 0x7fffu + ((x >> 16) & 1u);
  return (u16)(r >> 16);
}
DEV float bf2f(u16 u) { return __uint_as_float(((u32)u) << 16); }
DEV u16 f2h(float f) {
  _Float16 h = (_Float16)f;
  u16 u;
  __builtin_memcpy(&u, &h, 2);
  return u;
}
DEV float tanh_pos(float n) {  // tanh for n >= 0
  float e = __builtin_amdgcn_exp2f(2.8853900817779268f * n);  // e^(2n)
  return (e - 1.f) / (e + 1.f);
}
// hot-path pack: compiler lowers paired casts to v_cvt_pk_bf16_f32 (RNE)
DEV bf8_t conv8(float4 a, float4 b) {
  __hip_bfloat162 p[4] = {
      __float22bfloat162_rn(make_float2(a.x, a.y)),
      __float22bfloat162_rn(make_float2(a.z, a.w)),
      __float22bfloat162_rn(make_float2(b.x, b.y)),
      __float22bfloat162_rn(make_float2(b.z, b.w))};
  bf8_t o;
  __builtin_memcpy(&o, p, 16);
  return o;
}
DEV float dot4(float4 a) { return a.x * a.x + a.y * a.y + a.z * a.z + a.w * a.w; }

// ---------------- QKV GEMM, 32x64 tiles (768 blocks = 3/CU, no tail) -------
// z=0: q -> hq bf16 + qn2 ; z=1: k -> hk + kn2 ; z=2: v -> vT f16 + Wo conv.
// Logmap applied post-GEMM via linearity; expmap epilogue uses LDS cross-wave
// combine (row's 64 cols split across wave pairs ncol=0/32).
__global__ __launch_bounds__(256) void gemm_qkv_f3(
    const float* __restrict__ q, const float* __restrict__ k,
    const float* __restrict__ v, const float* __restrict__ Wq,
    const float* __restrict__ Wk, const float* __restrict__ Wv,
    const float* __restrict__ Wo, const float* __restrict__ bq,
    const float* __restrict__ bk, const float* __restrict__ bv,
    u16* __restrict__ hq, u16* __restrict__ hk, u16* __restrict__ vT,
    float* __restrict__ qn2, float* __restrict__ kn2,
    u16* __restrict__ wobf) {
  const int z = blockIdx.z;
  const float* A = z == 0 ? q : (z == 1 ? k : v);
  const float* W = z == 0 ? Wq : (z == 1 ? Wk : Wv);
  const float* bias = z == 0 ? bq : (z == 1 ? bk : bv);
  const int i0 = blockIdx.y * 32, j0 = blockIdx.x * 64, h = blockIdx.x;
  __shared__ __align__(16) u16 As[2048], Bs[4096];
  __shared__ float facs[32];
  __shared__ float pn[4][16], pn2[4][16];
  const int tid = threadIdx.x;
  const int w = tid >> 6, l = tid & 63, lg = l >> 4, lr = l & 15;
  const int srow = tid >> 3, scb = tid & 7;  // srow 0..31
  const int mrow = (w >> 1) * 16, ncol = (w & 1) * 32;
  if (z == 2) {  // side job: Wo fp32 -> bf16 (no LDS interaction)
    const int bid = blockIdx.y * 8 + blockIdx.x;  // 0..255
    const int off = bid * 1024 + tid * 4;
    float4 wa = *(const float4*)(Wo + off);
    __hip_bfloat162 p[2] = {__float22bfloat162_rn(make_float2(wa.x, wa.y)),
                            __float22bfloat162_rn(make_float2(wa.z, wa.w))};
    ushort4 o4;
    __builtin_memcpy(&o4, p, 8);
    *(ushort4*)(wobf + off) = o4;
  }
  f4_t acc[2] = {{0, 0, 0, 0}, {0, 0, 0, 0}};
  float n2 = 0.f;  // row-norm^2 partial (this thread's 8 cols per k-step)
  for (int kt = 0; kt < D; kt += 64) {
    const float* ap = A + (size_t)(i0 + srow) * D + kt + scb * 8;
    const float* wp0 = W + (size_t)(j0 + srow) * D + kt + scb * 8;
    const float* wp1 = wp0 + (size_t)32 * D;
    float4 a0 = *(const float4*)ap, a1 = *(const float4*)(ap + 4);
    float4 w00 = *(const float4*)wp0, w01 = *(const float4*)(wp0 + 4);
    float4 w10 = *(const float4*)wp1, w11 = *(const float4*)(wp1 + 4);
    n2 += dot4(a0) + dot4(a1);
    __syncthreads();  // previous iteration's LDS frag reads done
    const int sw = 8 * (scb ^ (srow & 7));
    *(bf8_t*)&As[srow * 64 + sw] = conv8(a0, a1);
    *(bf8_t*)&Bs[srow * 64 + sw] = conv8(w00, w01);
    *(bf8_t*)&Bs[(srow + 32) * 64 + sw] = conv8(w10, w11);
    __syncthreads();
#pragma unroll
    for (int ks = 0; ks < 2; ++ks) {
      const int arow = mrow + lr;
      bf8_t af = *(const bf8_t*)&As[arow * 64 + 8 * ((ks * 4 + lg) ^ (arow & 7))];
#pragma unroll
      for (int nf = 0; nf < 2; ++nf) {
        const int brow = ncol + nf * 16 + lr;
        bf8_t bfr = *(const bf8_t*)&Bs[brow * 64 + 8 * ((ks * 4 + lg) ^ (brow & 7))];
        acc[nf] = __builtin_amdgcn_mfma_f32_16x16x32_bf16(af, bfr, acc[nf], 0, 0, 0);
      }
    }
  }
  // row logmap factors: reduce norm^2 over the 8 scb lanes (consecutive)
  n2 += __shfl_xor(n2, 1, 64); n2 += __shfl_xor(n2, 2, 64);
  n2 += __shfl_xor(n2, 4, 64);
  if (scb == 0) {
    float na = fmaxf(sqrtf(n2), EPSF), za = fminf(na, 1.0f - EPSF);
    facs[srow] = 0.34657359027997264f *
                 __builtin_amdgcn_logf((1.0f + za) / (1.0f - za)) / na;
  }
  __syncthreads();
  float c[2][4];
#pragma unroll
  for (int nf = 0; nf < 2; ++nf) {
    const float bb = bias[j0 + ncol + nf * 16 + lr];
#pragma unroll
    for (int r = 0; r < 4; ++r)
      c[nf][r] = acc[nf][r] * facs[mrow + lg * 4 + r] + bb;
  }
  if (z < 2) {
    // --- per-head expmap: row norm over 64 cols, split across wave pair ---
    float part[4] = {0, 0, 0, 0};
#pragma unroll
    for (int nf = 0; nf < 2; ++nf)
#pragma unroll
      for (int r = 0; r < 4; ++r) part[r] += c[nf][r] * c[nf][r];
#pragma unroll
    for (int off = 1; off < 16; off <<= 1)
#pragma unroll
      for (int r = 0; r < 4; ++r) part[r] += __shfl_xor(part[r], off, 64);
    if (lr == 0)
#pragma unroll
      for (int r = 0; r < 4; ++r) pn[w][lg * 4 + r] = part[r];
    __syncthreads();
    float fac2[4];
#pragma unroll
    for (int r = 0; r < 4; ++r) {
      float n2f = pn[w][lg * 4 + r] + pn[w ^ 1][lg * 4 + r];
      float n = fmaxf(sqrtf(n2f), EPSF);
      fac2[r] = fminf(tanh_pos(n), MAXN) / n;
    }
    u16 yb[2][4];
    float p2[4] = {0, 0, 0, 0};
#pragma unroll
    for (int nf = 0; nf < 2; ++nf)
#pragma unroll
      for (int r = 0; r < 4; ++r) {
        u16 t = f2bf(c[nf][r] * fac2[r]);
        yb[nf][r] = t;
        float yf = bf2f(t);
        p2[r] += yf * yf;  // norm^2 of the rounded point
      }
#pragma unroll
    for (int off = 1; off < 16; off <<= 1)
#pragma unroll
      for (int r = 0; r < 4; ++r) p2[r] += __shfl_xor(p2[r], off, 64);
    if (lr == 0)
#pragma unroll
      for (int r = 0; r < 4; ++r) pn2[w][lg * 4 + r] = p2[r];
    u16* dst = z == 0 ? hq : hk;
    float* n2o = z == 0 ? qn2 : kn2;
#pragma unroll
    for (int nf = 0; nf < 2; ++nf)
#pragma unroll
      for (int r = 0; r < 4; ++r)
        dst[(size_t)(i0 + mrow + lg * 4 + r) * D + j0 + ncol + nf * 16 + lr] =
            yb[nf][r];
    __syncthreads();
    if (lr == 0 && (w & 1) == 0)
#pragma unroll
      for (int r = 0; r < 4; ++r)
        n2o[h * BS + i0 + mrow + lg * 4 + r] =
            pn2[w][lg * 4 + r] + pn2[w ^ 1][lg * 4 + r];
  } else {
    // V: f16, transpose via LDS -> vT[(b*8+h)*64 + d][s] (32-token slab)
    __syncthreads();  // all MFMA LDS reads done before reuse of As
#pragma unroll
    for (int nf = 0; nf < 2; ++nf)
#pragma unroll
      for (int r = 0; r < 4; ++r) {
        const int prow = mrow + lg * 4 + r;     // local token s (0..31)
        const int pcol = ncol + nf * 16 + lr;   // local d (0..63)
        As[prow * 64 + 8 * ((pcol >> 3) ^ (prow & 7)) + (pcol & 7)] = f2h(c[nf][r]);
      }
    __syncthreads();
    const int d = tid >> 2, s0 = (tid & 3) * 8;
    const int b = i0 >> 9, sb = (i0 & 511) + s0;
    bf8_t o0;
#pragma unroll
    for (int j = 0; j < 8; ++j) {
      const int s = s0 + j;
      o0[j] = (short)As[s * 64 + 8 * ((d >> 3) ^ (s & 7)) + (d & 7)];
    }
    *(bf8_t*)(vT + ((size_t)((b * 8 + h) * 64 + d)) * S + sb) = o0;
  }
}

// ---------------- fused attention: 4 K-split waves per block, LDS combine --
__global__ __launch_bounds__(256) void fused_attn_blk(
    const u16* __restrict__ hq, const u16* __restrict__ hk,
    const u16* __restrict__ vT, const float* __restrict__ qn2,
    const float* __restrict__ kn2, u16* __restrict__ ctx) {
  const int bh = blockIdx.y, b = bh >> 3, h = bh & 7;
  const int i0 = blockIdx.x * 16;
  __shared__ __align__(16) u16 Ps[4][2][1024];  // per-wave P bounce (16 KB)
  __shared__ float rsL[4][16];
  const int tid = threadIdx.x;
  const int w = tid >> 6, l = tid & 63, lg = l >> 4, lr = l & 15;
  const int sp = w;  // this wave's K-split
  bf8_t qf[2];
#pragma unroll
  for (int ks = 0; ks < 2; ++ks)
    qf[ks] = *(const bf8_t*)(hq + (size_t)(b * S + i0 + lr) * D + h * 64 +
                             ks * 32 + lg * 8);
  float qq[4];
#pragma unroll
  for (int r = 0; r < 4; ++r) qq[r] = qn2[h * BS + b * S + i0 + lg * 4 + r];
  f4_t acc_o[4] = {{0, 0, 0, 0}, {0, 0, 0, 0}, {0, 0, 0, 0}, {0, 0, 0, 0}};
  float rloc[4] = {0, 0, 0, 0};
#pragma unroll
  for (int t = 0; t < 2; ++t) {
    const int kt = sp * 2 + t;
    const int kb = b * S + kt * 64;
    bf8_t kf[2][4], vf[2][4];
#pragma unroll
    for (int ks = 0; ks < 2; ++ks)
#pragma unroll
      for (int nf = 0; nf < 4; ++nf) {
        kf[ks][nf] = *(const bf8_t*)(hk + (size_t)(kb + nf * 16 + lr) * D +
                                     h * 64 + ks * 32 + lg * 8);
        vf[ks][nf] = *(const bf8_t*)(vT + (size_t)(bh * 64 + nf * 16 + lr) * S +
                                     kt * 64 + ks * 32 + lg * 8);
      }
    float kn[4];
#pragma unroll
    for (int nf = 0; nf < 4; ++nf) kn[nf] = kn2[h * BS + kb + nf * 16 + lr];
    f4_t sa[4] = {{0, 0, 0, 0}, {0, 0, 0, 0}, {0, 0, 0, 0}, {0, 0, 0, 0}};
#pragma unroll
    for (int ks = 0; ks < 2; ++ks)
#pragma unroll
      for (int nf = 0; nf < 4; ++nf)
        sa[nf] = __builtin_amdgcn_mfma_f32_16x16x32_bf16(qf[ks], kf[ks][nf],
                                                         sa[nf], 0, 0, 0);
    u16* Pb = Ps[w][t & 1];
    float ps[4] = {0, 0, 0, 0};
#pragma unroll
    for (int nf = 0; nf < 4; ++nf) {
      const float kk = kn[nf];
#pragma unroll
      for (int r = 0; r < 4; ++r) {
        const float tt = sa[nf][r];
        float num = fmaxf(qq[r] - 2.f * tt + kk, 0.f);
        float den = fmaxf(1.f - 2.f * tt + qq[r] * kk, EPSF);
        float rr = fminf(fmaxf(sqrtf(num / den), EPSF), MAXN);
        // p = ((1-r)/(1+r))^(1/8)
        float p = __builtin_amdgcn_exp2f(
            0.125f * __builtin_amdgcn_logf((1.f - rr) / (1.f + rr)));
        ps[r] += p;
        const int prow = lg * 4 + r, pcol = nf * 16 + lr;
        Pb[prow * 64 + 8 * ((pcol >> 3) ^ (prow & 7)) + (pcol & 7)] = f2h(p);
      }
    }
#pragma unroll
    for (int off = 1; off < 16; off <<= 1)
#pragma unroll
      for (int r = 0; r < 4; ++r) ps[r] += __shfl_xor(ps[r], off, 64);
#pragma unroll
    for (int r = 0; r < 4; ++r) rloc[r] += ps[r];
#pragma unroll
    for (int ks = 0; ks < 2; ++ks) {
      h8_t pa = *(const h8_t*)&Pb[lr * 64 + 8 * ((ks * 4 + lg) ^ (lr & 7))];
#pragma unroll
      for (int nf = 0; nf < 4; ++nf)
        acc_o[nf] = __builtin_amdgcn_mfma_f32_16x16x32_f16(pa, vf[ks][nf],
                                                           acc_o[nf], 0, 0, 0);
    }
  }
  // drop this wave's fp32 partial into its own (now-dead) P region
  float* myO = (float*)Ps + w * 1024;  // [16][64] floats == Ps[w] bytes
#pragma unroll
  for (int nf = 0; nf < 4; ++nf)
#pragma unroll
    for (int r = 0; r < 4; ++r)
      myO[(lg * 4 + r) * 64 + nf * 16 + lr] = acc_o[nf][r];
  if (lr == 0)
#pragma unroll
    for (int r = 0; r < 4; ++r) rsL[w][lg * 4 + r] = rloc[r];
  __syncthreads();
  // cooperative combine: 16 rows x 64 cols, 4 elems/thread
  const float* OsL = (const float*)Ps;
  const int row = tid >> 4, c4 = (tid & 15) * 4;
  const float rt = rsL[0][row] + rsL[1][row] + rsL[2][row] + rsL[3][row];
  const float inv = 1.f / rt;
  f4_t s = {0, 0, 0, 0};
#pragma unroll
  for (int sp2 = 0; sp2 < 4; ++sp2)
    s += *(const f4_t*)&OsL[sp2 * 1024 + row * 64 + c4];
  __hip_bfloat162 p[2] = {
      __float22bfloat162_rn(make_float2(s[0] * inv, s[1] * inv)),
      __float22bfloat162_rn(make_float2(s[2] * inv, s[3] * inv))};
  ushort4 o;
  __builtin_memcpy(&o, p, 8);
  *(ushort4*)&ctx[(size_t)(b * S + i0 + row) * D + h * 64 + c4] = o;
}

// ---------------- out projection: ctx(bf16) @ WoBf^T + bo, 32x64 tiles -----
__global__ __launch_bounds__(256) void gemm_out_b(
    const u16* __restrict__ A, const u16* __restrict__ Wob,
    const float* __restrict__ bias, float* __restrict__ C) {
  const int i0 = blockIdx.y * 32, j0 = blockIdx.x * 64;
  __shared__ __align__(16) u16 As[2048], Bs[4096];
  const int tid = threadIdx.x;
  const int w = tid >> 6, l = tid & 63, lg = l >> 4, lr = l & 15;
  const int srow = tid >> 3, scb = tid & 7;  // srow 0..31
  const int mrow = (w >> 1) * 16, ncol = (w & 1) * 32;
  f4_t acc[2] = {{0, 0, 0, 0}, {0, 0, 0, 0}};
  for (int kt = 0; kt < D; kt += 64) {
    bf8_t a0 = *(const bf8_t*)(A + (size_t)(i0 + srow) * D + kt + scb * 8);
    bf8_t w0 = *(const bf8_t*)(Wob + (size_t)(j0 + srow) * D + kt + scb * 8);
    bf8_t w1 = *(const bf8_t*)(Wob + (size_t)(j0 + srow + 32) * D + kt + scb * 8);
    __syncthreads();
    const int sw = 8 * (scb ^ (srow & 7));
    *(bf8_t*)&As[srow * 64 + sw] = a0;
    *(bf8_t*)&Bs[srow * 64 + sw] = w0;
    *(bf8_t*)&Bs[(srow + 32) * 64 + sw] = w1;
    __syncthreads();
#pragma unroll
    for (int ks = 0; ks < 2; ++ks) {
      const int arow = mrow + lr;
      bf8_t af = *(const bf8_t*)&As[arow * 64 + 8 * ((ks * 4 + lg) ^ (arow & 7))];
#pragma unroll
      for (int nf = 0; nf < 2; ++nf) {
        const int brow = ncol + nf * 16 + lr;
        bf8_t bfr = *(const bf8_t*)&Bs[brow * 64 + 8 * ((ks * 4 + lg) ^ (brow & 7))];
        acc[nf] = __builtin_amdgcn_mfma_f32_16x16x32_bf16(af, bfr, acc[nf], 0, 0, 0);
      }
    }
  }
#pragma unroll
  for (int nf = 0; nf < 2; ++nf) {
    const int j = j0 + ncol + nf * 16 + lr;
    const float bb = bias[j];
#pragma unroll
    for (int r = 0; r < 4; ++r)
      C[(size_t)(i0 + mrow + lg * 4 + r) * D + j] = acc[nf][r] + bb;
  }
}

// ---------------- final expmap0 over full rows (512) -> d_out --------------
__global__ __launch_bounds__(256) void expmap_rows_full(
    const float* __restrict__ in, float* __restrict__ out) {
  const int row = blockIdx.x;
  const float2 xv = *(const float2*)(in + (size_t)row * D + threadIdx.x * 2);
  float s = xv.x * xv.x + xv.y * xv.y;
  __shared__ float sh[4];
  float ws = waveSum(s);
  if ((threadIdx.x & 63) == 0) sh[threadIdx.x >> 6] = ws;
  __syncthreads();
  float tot = sh[0] + sh[1] + sh[2] + sh[3];
  float n = fmaxf(sqrtf(tot), EPSF);
  float fac = fminf(tanh_pos(n), MAXN) / n;
  float2 o = make_float2(xv.x * fac, xv.y * fac);
  *(float2*)(out + (size_t)row * D + threadIdx.x * 2) = o;
}

}  // namespace

extern "C" void kernel_launch(void* const* d_in, const int* in_sizes, int n_in,
                              void* d_out, int out_size, void* d_ws,
                              size_t ws_size, hipStream_t stream) {
  const float* q = (const float*)d_in[0];
  const float* k = (const float*)d_in[1];
  const float* v = (const float*)d_in[2];
  const float* Wq = (const float*)d_in[3];
  const float* bq = (const float*)d_in[4];
  const float* Wk = (const float*)d_in[5];
  const float* bk = (const float*)d_in[6];
  const float* Wv = (const float*)d_in[7];
  const float* bv = (const float*)d_in[8];
  const float* Wo = (const float*)d_in[9];
  const float* bo = (const float*)d_in[10];
  float* out = (float*)d_out;

  char* w8 = (char*)d_ws;
  u16* hq = (u16*)(w8 + 0);                 // 1 MB
  u16* hk = (u16*)(w8 + 1048576);           // 1 MB
  u16* vT = (u16*)(w8 + 2097152);           // 1 MB  [bh*64+d][s] f16
  float* qn2 = (float*)(w8 + 3145728);      // 32 KB [H][BS]
  float* kn2 = (float*)(w8 + 3178496);      // 32 KB [H][BS]
  u16* ctx = (u16*)(w8 + 3211264);          // 1 MB  bf16
  float* olin = (float*)(w8 + 4259840);     // 2 MB  fp32
  u16* wobf = (u16*)(w8 + 6357504);         // 512 KB bf16 Wo

  gemm_qkv_f3<<<dim3(8, 32, 3), 256, 0, stream>>>(
      q, k, v, Wq, Wk, Wv, Wo, bq, bk, bv, hq, hk, vT, qn2, kn2, wobf);
  fused_attn_blk<<<dim3(32, 16), 256, 0, stream>>>(hq, hk, vT, qn2, kn2, ctx);
  gemm_out_b<<<dim3(8, 32), 256, 0, stream>>>(ctx, wobf, bo, olin);
  expmap_rows_full<<<dim3(BS), 256, 0, stream>>>(olin, out);
}